// Round 12
// baseline (217.984 us; speedup 1.0000x reference)
//
#include <hip/hip_runtime.h>

#define NN 25600      // nodes = 160*160
#define HH 160
#define WW 160
#define C2 256
#define MSLOTS 64     // colsum atomic spreading slots

// ---- bf16 weight pack offsets (ushorts) ----
#define B_WIN   0
#define B_WID   32768
#define B_WGAT  65536      // 2 layers x 65536
#define B_WOUT  196608
#define B_WEND  262144

// ---- small fp32 param offsets inside cvt (floats) ----
#define C_BNA   0          // 2x256 BN scale
#define C_BNB   512        // 2x256 BN shift (bias/mean folded)
#define C_ASRC  1024       // 2x256
#define C_ADST  1536       // 2x256
#define C_SEW1  2048       // 64x256
#define C_SEB1  18432      // 64
#define C_SEW2  18496      // 256x64
#define C_SEB2  34880      // 256
#define C_END   35136

typedef __attribute__((ext_vector_type(8))) short bfrag;   // 8 bf16 (4 VGPRs)
typedef __attribute__((ext_vector_type(4))) float ffrag;   // 4 fp32 acc

__device__ __forceinline__ float b2f(unsigned short u) {
    union { unsigned int ui; float f; } v; v.ui = ((unsigned int)u) << 16; return v.f;
}
__device__ __forceinline__ unsigned short f2b(float f) {
    union { float f; unsigned int u; } v; v.f = f;
    unsigned int u = v.u;
    unsigned int r = (u + 0x7FFFu + ((u >> 16) & 1u)) >> 16;
    return (unsigned short)r;
}
__device__ __forceinline__ float lo16f(unsigned int w) {
    union { unsigned int ui; float f; } v; v.ui = w << 16; return v.f;
}
__device__ __forceinline__ float hi16f(unsigned int w) {
    union { unsigned int ui; float f; } v; v.ui = w & 0xFFFF0000u; return v.f;
}
// Wave-uniform dtype probe on first 512 halfwords of x.
__device__ __forceinline__ bool probe_f32(const unsigned short* __restrict__ x) {
    int l = threadIdx.x & 63;
    bool wild = false;
#pragma unroll
    for (int i = 0; i < 8; ++i) {
        float v = b2f(x[l * 8 + i]);
        wild |= !(fabsf(v) < 1e6f);
    }
    return __any(wild);
}
__device__ __forceinline__ float ldf(const void* p, long i, bool f32) {
    return f32 ? ((const float*)p)[i] : b2f(((const unsigned short*)p)[i]);
}

// Swizzled fragment pointers into unpadded LDS tiles staged by global_load_lds:
// chunk (16B) index XOR'd with (row&7) on BOTH the pre-swizzled global source
// and the read side (rule: both-sides-or-neither).
__device__ __forceinline__ const bfrag* fragp(const unsigned short* buf, int row, int c8) {
    return (const bfrag*)(buf + row * 64 + ((c8 ^ (row & 7)) << 3));     // [64][64] tile
}
__device__ __forceinline__ const bfrag* fragp128(const unsigned short* buf, int row, int c8) {
    return (const bfrag*)(buf + row * 128 + ((c8 ^ (row & 7)) << 3));    // [64][128] tile
}

// ---------------------------------------------------------------------------
// prep: pack weights bf16, fold BN, convert small params, zero means slots,
// AND transpose x -> bf16 [25600][128]. Grid = 400.
// ---------------------------------------------------------------------------
__global__ __launch_bounds__(256) void prep_kernel(
    const unsigned short* __restrict__ xp,
    const void* pwin, const void* pwid, const void* pwgat, const void* pwout,
    const void* pasrc, const void* padst, const void* pgbias,
    const void* pbng, const void* pbnb, const void* pbnm, const void* pbnv,
    const void* psew1, const void* pseb1, const void* psew2, const void* pseb2,
    unsigned short* __restrict__ wb, float* __restrict__ cvt,
    float* __restrict__ means, unsigned short* __restrict__ xT)
{
    __shared__ unsigned short T[64 * 136];
    const bool f32 = probe_f32(xp);
    const int tid = threadIdx.x;
    const int bid = blockIdx.x;
    const int gid = bid * 256 + tid;
    const int stride = gridDim.x * 256;

    for (int i = gid; i < MSLOTS * 256; i += stride) means[i] = 0.f;

    for (int i = gid; i < B_WEND; i += stride) {
        const void* s; int o;
        if      (i < B_WID)   { s = pwin;  o = i - B_WIN; }
        else if (i < B_WGAT)  { s = pwid;  o = i - B_WID; }
        else if (i < B_WOUT)  { s = pwgat; o = i - B_WGAT; }
        else                  { s = pwout; o = i - B_WOUT; }
        wb[i] = f32 ? f2b(((const float*)s)[o]) : ((const unsigned short*)s)[o];
    }
    for (int i = gid; i < 512; i += stride) {
        float sc = ldf(pbng, i, f32) * rsqrtf(ldf(pbnv, i, f32) + 1e-5f);
        cvt[C_BNA + i] = sc;
        cvt[C_BNB + i] = (ldf(pgbias, i, f32) - ldf(pbnm, i, f32)) * sc + ldf(pbnb, i, f32);
        cvt[C_ASRC + i] = ldf(pasrc, i, f32);
        cvt[C_ADST + i] = ldf(padst, i, f32);
    }
    for (int i = gid; i < 16384; i += stride) {
        cvt[C_SEW1 + i] = ldf(psew1, i, f32);
        cvt[C_SEW2 + i] = ldf(psew2, i, f32);
    }
    for (int i = gid; i < 64; i += stride)  cvt[C_SEB1 + i] = ldf(pseb1, i, f32);
    for (int i = gid; i < 256; i += stride) cvt[C_SEB2 + i] = ldf(pseb2, i, f32);

    // transpose slice: 64 nodes per block
    {
        const int n0 = bid * 64;
        const int nl = tid & 63;
#pragma unroll
        for (int i = 0; i < 32; ++i) {
            int c = i * 4 + (tid >> 6);
            long idx = (long)c * NN + n0 + nl;
            T[nl * 136 + c] = f32 ? f2b(((const float*)xp)[idx]) : xp[idx];
        }
        __syncthreads();
#pragma unroll
        for (int i = 0; i < 4; ++i) {
            int n = tid >> 2, c0 = (tid & 3) * 32 + i * 8;
            uint4 v = *(const uint4*)&T[n * 136 + c0];
            *(uint4*)(xT + (long)(n0 + n) * 128 + c0) = v;
        }
    }
}

// ---------------------------------------------------------------------------
// LDS layouts. Staging tiles UNPADDED (global_load_lds lane-linear dest);
// bank conflicts broken by XOR chunk swizzle. C-staging keeps padded rows.
// ---------------------------------------------------------------------------
struct SmemC64  { unsigned short Cs[64 * 72]; };                     //  9216 B
struct SmemG2u  { unsigned short As[4096], Bi[4096], Bd[4096]; };    // 24576 B
union  SmemXu   { SmemG2u g; SmemC64 c; };
struct SmemGw   { unsigned short As[8192], Bs[8192]; };              // 32768 B ([64][128] x2)
union  SmemNw   { SmemGw g; SmemC64 c; };
struct SmemT    { float T[64 * 73]; };                               // 18688 B
union  SmemFw   { SmemGw g; SmemT t; };

// Stage a [64][64]-ushort tile via global_load_lds (pre-swizzled source chunk).
#define STAGE_TILE(DST, SRC, ROW0, LDA, K0)                                       \
    {                                                                             \
        _Pragma("unroll")                                                         \
        for (int ii = 0; ii < 2; ++ii) {                                          \
            int e = tid + ii * 256;                                               \
            int row = e >> 3;                                                     \
            int q = (e & 7) ^ (row & 7);                                          \
            __builtin_amdgcn_global_load_lds(                                     \
                (const unsigned int*)((SRC) + (long)((ROW0) + row) * (LDA) + (K0) + q * 8), \
                (unsigned int*)&(DST)[e * 8], 16, 0, 0);                          \
        }                                                                         \
    }

// Stage a [64][128]-ushort tile (16 chunks/row) the same way.
#define STAGE_TILE128(DST, SRC, ROW0, LDA, K0)                                    \
    {                                                                             \
        _Pragma("unroll")                                                         \
        for (int ii = 0; ii < 4; ++ii) {                                          \
            int e = tid + ii * 256;                                               \
            int row = e >> 4;                                                     \
            int q = (e & 15) ^ (row & 7);                                         \
            __builtin_amdgcn_global_load_lds(                                     \
                (const unsigned int*)((SRC) + (long)((ROW0) + row) * (LDA) + (K0) + q * 8), \
                (unsigned int*)&(DST)[e * 8], 16, 0, 0);                          \
        }                                                                         \
    }

// ---------------------------------------------------------------------------
// MFMA GEMM (dual-B, K=128): xf16=A@Wi^T, idb16=A@Wd^T. Grid (400,4), 256 thr.
// M-tile 64, BK=64 (2 k-steps). Staging via global_load_lds (async DMA).
// ---------------------------------------------------------------------------
__global__ __launch_bounds__(256) void mfma_gemm_x2_kernel(
    const unsigned short* __restrict__ A16,
    const unsigned short* __restrict__ Wi16,
    const unsigned short* __restrict__ Wd16,
    unsigned short* __restrict__ xf16,
    unsigned short* __restrict__ idb16)
{
    __shared__ SmemXu sm;
    const int tid = threadIdx.x;
    const int m0 = blockIdx.x * 64, o0 = blockIdx.y * 64;
    const int lane = tid & 63, wv = tid >> 6;
    const int wm = wv >> 1, wn = wv & 1;
    const int lr = lane & 15, quad = lane >> 4;

    ffrag ai[2][2], ad[2][2];
#pragma unroll
    for (int mt = 0; mt < 2; ++mt)
#pragma unroll
        for (int nt = 0; nt < 2; ++nt) { ai[mt][nt] = (ffrag){0,0,0,0}; ad[mt][nt] = (ffrag){0,0,0,0}; }

    for (int k0 = 0; k0 < 128; k0 += 64) {
        STAGE_TILE(sm.g.As, A16,  m0, 128, k0)
        STAGE_TILE(sm.g.Bi, Wi16, o0, 128, k0)
        STAGE_TILE(sm.g.Bd, Wd16, o0, 128, k0)
        __syncthreads();   // drains vmcnt (DMA complete) before ds_reads
#pragma unroll
        for (int ks = 0; ks < 2; ++ks) {
            bfrag a[2], bi[2], bd[2];
#pragma unroll
            for (int mt = 0; mt < 2; ++mt)
                a[mt] = *fragp(sm.g.As, wm * 32 + mt * 16 + lr, ks * 4 + quad);
#pragma unroll
            for (int nt = 0; nt < 2; ++nt) {
                bi[nt] = *fragp(sm.g.Bi, wn * 32 + nt * 16 + lr, ks * 4 + quad);
                bd[nt] = *fragp(sm.g.Bd, wn * 32 + nt * 16 + lr, ks * 4 + quad);
            }
#pragma unroll
            for (int mt = 0; mt < 2; ++mt)
#pragma unroll
                for (int nt = 0; nt < 2; ++nt) {
                    ai[mt][nt] = __builtin_amdgcn_mfma_f32_16x16x32_bf16(a[mt], bi[nt], ai[mt][nt], 0, 0, 0);
                    ad[mt][nt] = __builtin_amdgcn_mfma_f32_16x16x32_bf16(a[mt], bd[nt], ad[mt][nt], 0, 0, 0);
                }
        }
        __syncthreads();
    }
    // epilogue 1: xf16
#pragma unroll
    for (int mt = 0; mt < 2; ++mt)
#pragma unroll
        for (int nt = 0; nt < 2; ++nt)
#pragma unroll
            for (int r = 0; r < 4; ++r)
                sm.c.Cs[(wm * 32 + mt * 16 + quad * 4 + r) * 72 + wn * 32 + nt * 16 + lr] = f2b(ai[mt][nt][r]);
    __syncthreads();
#pragma unroll
    for (int it = 0; it < 2; ++it) {
        int e = it * 256 + tid;
        int row = e >> 3, c8 = (e & 7) * 8;
        *(uint4*)(xf16 + (long)(m0 + row) * C2 + o0 + c8) = *(const uint4*)&sm.c.Cs[row * 72 + c8];
    }
    __syncthreads();
    // epilogue 2: idb16
#pragma unroll
    for (int mt = 0; mt < 2; ++mt)
#pragma unroll
        for (int nt = 0; nt < 2; ++nt)
#pragma unroll
            for (int r = 0; r < 4; ++r)
                sm.c.Cs[(wm * 32 + mt * 16 + quad * 4 + r) * 72 + wn * 32 + nt * 16 + lr] = f2b(ad[mt][nt][r]);
    __syncthreads();
#pragma unroll
    for (int it = 0; it < 2; ++it) {
        int e = it * 256 + tid;
        int row = e >> 3, c8 = (e & 7) * 8;
        *(uint4*)(idb16 + (long)(m0 + row) * C2 + o0 + c8) = *(const uint4*)&sm.c.Cs[row * 72 + c8];
    }
}

// ---------------------------------------------------------------------------
// GAT GEMM (K=256): h = xf@W^T + fused attention scores. Grid (400,4), 256 thr.
// M-tile 64, BK=128 (2 K-steps, 4 barriers total). Staging via global_load_lds.
// ---------------------------------------------------------------------------
__global__ __launch_bounds__(256) void gat_gemm_kernel(
    const unsigned short* __restrict__ A16,
    const unsigned short* __restrict__ W16,
    unsigned short* __restrict__ Cout,
    const float* __restrict__ asrc, const float* __restrict__ adst,
    float* __restrict__ als_out, float* __restrict__ ald_out)
{
    __shared__ SmemNw sm;
    const int tid = threadIdx.x;
    const int m0 = blockIdx.x * 64, o0 = blockIdx.y * 64;
    const int lane = tid & 63, wv = tid >> 6;
    const int wm = wv >> 1, wn = wv & 1;
    const int lr = lane & 15, quad = lane >> 4;

    ffrag acc[2][2];
#pragma unroll
    for (int mt = 0; mt < 2; ++mt)
#pragma unroll
        for (int nt = 0; nt < 2; ++nt) acc[mt][nt] = (ffrag){0,0,0,0};

    for (int k0 = 0; k0 < 256; k0 += 128) {
        STAGE_TILE128(sm.g.As, A16, m0, C2, k0)
        STAGE_TILE128(sm.g.Bs, W16, o0, C2, k0)
        __syncthreads();
#pragma unroll
        for (int ks = 0; ks < 4; ++ks) {
            bfrag a[2], b[2];
#pragma unroll
            for (int mt = 0; mt < 2; ++mt)
                a[mt] = *fragp128(sm.g.As, wm * 32 + mt * 16 + lr, ks * 4 + quad);
#pragma unroll
            for (int nt = 0; nt < 2; ++nt)
                b[nt] = *fragp128(sm.g.Bs, wn * 32 + nt * 16 + lr, ks * 4 + quad);
#pragma unroll
            for (int mt = 0; mt < 2; ++mt)
#pragma unroll
                for (int nt = 0; nt < 2; ++nt)
                    acc[mt][nt] = __builtin_amdgcn_mfma_f32_16x16x32_bf16(a[mt], b[nt], acc[mt][nt], 0, 0, 0);
        }
        __syncthreads();
    }
    // attention epilogue: wave covers head = by*2+wn, d = nt*16+lr
    {
        const int head = blockIdx.y * 2 + wn;
        const float as0 = asrc[head * 32 + lr], as1 = asrc[head * 32 + 16 + lr];
        const float ad0 = adst[head * 32 + lr], ad1 = adst[head * 32 + 16 + lr];
#pragma unroll
        for (int mt = 0; mt < 2; ++mt)
#pragma unroll
            for (int r = 0; r < 4; ++r) {
                float ps = acc[mt][0][r] * as0 + acc[mt][1][r] * as1;
                float pd = acc[mt][0][r] * ad0 + acc[mt][1][r] * ad1;
#pragma unroll
                for (int sh = 1; sh < 16; sh <<= 1) {
                    ps += __shfl_xor(ps, sh);
                    pd += __shfl_xor(pd, sh);
                }
                if (lr == 0) {
                    int m = m0 + wm * 32 + mt * 16 + quad * 4 + r;
                    als_out[m * 8 + head] = ps;
                    ald_out[m * 8 + head] = pd;
                }
            }
    }
    // C store via LDS
#pragma unroll
    for (int mt = 0; mt < 2; ++mt)
#pragma unroll
        for (int nt = 0; nt < 2; ++nt)
#pragma unroll
            for (int r = 0; r < 4; ++r)
                sm.c.Cs[(wm * 32 + mt * 16 + quad * 4 + r) * 72 + wn * 32 + nt * 16 + lr] = f2b(acc[mt][nt][r]);
    __syncthreads();
#pragma unroll
    for (int it = 0; it < 2; ++it) {
        int e = it * 256 + tid;
        int row = e >> 3, c8 = (e & 7) * 8;
        *(uint4*)(Cout + (long)(m0 + row) * C2 + o0 + c8) = *(const uint4*)&sm.c.Cs[row * 72 + c8];
    }
}

// ---------------------------------------------------------------------------
// Aggregation: 8 nodes/block, 32 thr/node, 8 bf16 channels/thread. Grid 3200.
// Gather loads batched into registers (11x uint4) so vmcnt overlaps them.
// If means != nullptr (last hop): block-reduce colsum -> atomicAdd into one
// of MSLOTS slots (spread: ~50 serialized RMWs/address instead of 3200).
// ---------------------------------------------------------------------------
__global__ __launch_bounds__(256) void aggregate_kernel(
    const unsigned short* __restrict__ h16,
    const float* __restrict__ al_s,
    const float* __restrict__ al_d,
    const float* __restrict__ bnA,
    const float* __restrict__ bnB,
    unsigned short* __restrict__ xf16,
    float* __restrict__ means)
{
    const int SI[11] = { 1, 1, 1, 0, 0, -1, -1, -1, -2,  0, 0};
    const int SJ[11] = { 1, 0,-1, 1,-1,  1,  0, -1,  0, -2, 0};
    __shared__ float es[8][11][8];
    __shared__ float alpha[8][11][8];
    __shared__ float part[4][256];

    const int t = threadIdx.x;
    const int ln = t >> 5;
    const int l = t & 31;
    const int n = blockIdx.x * 8 + ln;
    const int i = n / WW, j = n % WW;

    for (int idx = t; idx < 704; idx += 256) {
        int lln = idx / 88, rem = idx - lln * 88;
        int k = rem >> 3, hh = rem & 7;
        int nn2 = blockIdx.x * 8 + lln;
        int ii = nn2 / WW, jj = nn2 - ii * WW;
        int si = ii + SI[k], sj = jj + SJ[k];
        bool okk = (si >= 0) & (si < HH) & (sj >= 0) & (sj < WW);
        es[lln][k][hh] = okk ? al_s[(si * WW + sj) * 8 + hh] : -1e30f;
    }
    __syncthreads();

    if (l < 8) {
        const int hd = l;
        const float ald = al_d[n * 8 + hd];
        float e[11];
        float mx = -1e30f;
#pragma unroll
        for (int k = 0; k < 11; ++k) {
            float v = es[ln][k][hd] + ald;
            v = v > 0.f ? v : 0.2f * v;
            e[k] = v;
            mx = fmaxf(mx, v);
        }
        float denom = 0.f;
#pragma unroll
        for (int k = 0; k < 11; ++k) {
            float p = __expf(e[k] - mx);
            e[k] = p;
            denom += p;
        }
        const float inv = 1.f / (denom + 1e-16f);
#pragma unroll
        for (int k = 0; k < 11; ++k) alpha[ln][k][hd] = e[k] * inv;
    }
    __syncthreads();

    const int c8 = l * 8;
    const int hd = l >> 2;
    int srcn[11];
#pragma unroll
    for (int k = 0; k < 11; ++k) {
        int si = i + SI[k], sj = j + SJ[k];
        bool ok = (si >= 0) & (si < HH) & (sj >= 0) & (sj < WW);
        srcn[k] = ok ? si * WW + sj : n;
    }
    // batched gather: all 12 loads issued before any consumption
    uint4 hv[11];
#pragma unroll
    for (int k = 0; k < 11; ++k)
        hv[k] = *(const uint4*)(h16 + (long)srcn[k] * C2 + c8);
    uint4 rv = *(const uint4*)(xf16 + (long)n * C2 + c8);

    float a0=0.f,a1=0.f,a2=0.f,a3=0.f,a4=0.f,a5=0.f,a6=0.f,a7=0.f;
#pragma unroll
    for (int k = 0; k < 11; ++k) {
        float al = alpha[ln][k][hd];
        a0 += al * lo16f(hv[k].x); a1 += al * hi16f(hv[k].x);
        a2 += al * lo16f(hv[k].y); a3 += al * hi16f(hv[k].y);
        a4 += al * lo16f(hv[k].z); a5 += al * hi16f(hv[k].z);
        a6 += al * lo16f(hv[k].w); a7 += al * hi16f(hv[k].w);
    }
    float acc8[8] = {a0,a1,a2,a3,a4,a5,a6,a7};
    float res[8] = {lo16f(rv.x),hi16f(rv.x),lo16f(rv.y),hi16f(rv.y),
                    lo16f(rv.z),hi16f(rv.z),lo16f(rv.w),hi16f(rv.w)};
    float out[8];
#pragma unroll
    for (int q = 0; q < 8; ++q) {
        int c = c8 + q;
        float g = acc8[q] * bnA[c] + bnB[c];
        out[q] = fmaxf(g, 0.f) + res[q];
    }
    ushort4 o16a, o16b;
    o16a.x = f2b(out[0]); o16a.y = f2b(out[1]); o16a.z = f2b(out[2]); o16a.w = f2b(out[3]);
    o16b.x = f2b(out[4]); o16b.y = f2b(out[5]); o16b.z = f2b(out[6]); o16b.w = f2b(out[7]);
    *(ushort4*)(xf16 + (long)n * C2 + c8)     = o16a;
    *(ushort4*)(xf16 + (long)n * C2 + c8 + 4) = o16b;

    // fused colsum for SE (last hop only), atomic-spread over MSLOTS slots
    if (means) {
        float s8[8];
#pragma unroll
        for (int q = 0; q < 8; ++q) {
            s8[q] = out[q];
            s8[q] += __shfl_xor(s8[q], 32);    // combine node pair within wave
        }
        const int wvi = t >> 6;
        if ((t & 63) < 32) {
#pragma unroll
            for (int q = 0; q < 8; ++q) part[wvi][c8 + q] = s8[q];
        }
        __syncthreads();
        {
            float v = part[0][t] + part[1][t] + part[2][t] + part[3][t];
            atomicAdd(&means[(blockIdx.x & (MSLOTS - 1)) * 256 + t], v);
        }
    }
}

// ---------------------------------------------------------------------------
// SE vector, computed ONCE: cs = slot-sum(means); mv = cs@Wout^T / N;
// hv = relu(W1@mv + b1); sv = sigmoid(W2@hv + b2). Grid 1 x 256 thr.
// ---------------------------------------------------------------------------
__global__ __launch_bounds__(256) void se_kernel(
    const unsigned short* __restrict__ W16,     // Wout bf16 [256][256]
    const float* __restrict__ means,
    const float* __restrict__ cvt,
    float* __restrict__ sv_out)
{
    __shared__ float cs[256], mv[256], hv[64];
    const int t = threadIdx.x;
    {
        float s0=0,s1=0,s2=0,s3=0,s4=0,s5=0,s6=0,s7=0;
#pragma unroll 2
        for (int sl = 0; sl < MSLOTS; sl += 8) {
            s0 += means[(sl+0)*256 + t]; s1 += means[(sl+1)*256 + t];
            s2 += means[(sl+2)*256 + t]; s3 += means[(sl+3)*256 + t];
            s4 += means[(sl+4)*256 + t]; s5 += means[(sl+5)*256 + t];
            s6 += means[(sl+6)*256 + t]; s7 += means[(sl+7)*256 + t];
        }
        cs[t] = ((s0+s1)+(s2+s3)) + ((s4+s5)+(s6+s7));
    }
    __syncthreads();
    {
        float s = 0.f;
        const unsigned short* wr = W16 + (long)t * C2;
#pragma unroll 4
        for (int k = 0; k < 256; k += 8) {
            uint4 w = *(const uint4*)(wr + k);
            s += cs[k]   * lo16f(w.x) + cs[k+1] * hi16f(w.x)
               + cs[k+2] * lo16f(w.y) + cs[k+3] * hi16f(w.y)
               + cs[k+4] * lo16f(w.z) + cs[k+5] * hi16f(w.z)
               + cs[k+6] * lo16f(w.w) + cs[k+7] * hi16f(w.w);
        }
        mv[t] = s * (1.0f / 25600.0f);
    }
    __syncthreads();
    if (t < 64) {
        const float* w1 = cvt + C_SEW1 + t * 256;
        float s = cvt[C_SEB1 + t];
        for (int cc = 0; cc < 256; cc += 4) {
            float4 w = *(const float4*)(w1 + cc);
            s += w.x * mv[cc] + w.y * mv[cc+1] + w.z * mv[cc+2] + w.w * mv[cc+3];
        }
        hv[t] = fmaxf(s, 0.f);
    }
    __syncthreads();
    {
        const float* w2 = cvt + C_SEW2 + t * 64;
        float s = cvt[C_SEB2 + t];
        for (int k = 0; k < 64; k += 4) {
            float4 w = *(const float4*)(w2 + k);
            s += w.x * hv[k] + w.y * hv[k+1] + w.z * hv[k+2] + w.w * hv[k+3];
        }
        sv_out[t] = 1.0f / (1.0f + __expf(-s));
    }
}

// ---------------------------------------------------------------------------
// Final: y-tile = xf@Wout^T (64x64 per block), out[c][n] = y*sv + idb,
// transposed store. Grid (400,4), 256 thr. BK=128 staging via global_load_lds.
// ---------------------------------------------------------------------------
__global__ __launch_bounds__(256) void final_gemm_kernel(
    const unsigned short* __restrict__ x_probe,
    const unsigned short* __restrict__ A16,       // xf post-hop2
    const unsigned short* __restrict__ W16,       // Wout bf16 [256][256]
    const unsigned short* __restrict__ idb16,
    const float* __restrict__ sv,
    void* __restrict__ outp)
{
    __shared__ SmemFw sm;
    const bool f32o = probe_f32(x_probe);
    const int tid = threadIdx.x;
    const int m0 = blockIdx.x * 64, o0 = blockIdx.y * 64;
    const int lane = tid & 63, wv = tid >> 6;
    const int wm = wv >> 1, wn = wv & 1;
    const int lr = lane & 15, quad = lane >> 4;

    ffrag acc[2][2];
#pragma unroll
    for (int mt = 0; mt < 2; ++mt)
#pragma unroll
        for (int nt = 0; nt < 2; ++nt) acc[mt][nt] = (ffrag){0,0,0,0};

    for (int k0 = 0; k0 < 256; k0 += 128) {
        STAGE_TILE128(sm.g.As, A16, m0, C2, k0)
        STAGE_TILE128(sm.g.Bs, W16, o0, C2, k0)
        __syncthreads();
#pragma unroll
        for (int ks = 0; ks < 4; ++ks) {
            bfrag a[2], b[2];
#pragma unroll
            for (int mt = 0; mt < 2; ++mt)
                a[mt] = *fragp128(sm.g.As, wm * 32 + mt * 16 + lr, ks * 4 + quad);
#pragma unroll
            for (int nt = 0; nt < 2; ++nt)
                b[nt] = *fragp128(sm.g.Bs, wn * 32 + nt * 16 + lr, ks * 4 + quad);
#pragma unroll
            for (int mt = 0; mt < 2; ++mt)
#pragma unroll
                for (int nt = 0; nt < 2; ++nt)
                    acc[mt][nt] = __builtin_amdgcn_mfma_f32_16x16x32_bf16(a[mt], b[nt], acc[mt][nt], 0, 0, 0);
        }
        __syncthreads();
    }

    // deposit y*sv + idb into T[col][row] (fp32), then coalesced transposed store
#pragma unroll
    for (int mt = 0; mt < 2; ++mt)
#pragma unroll
        for (int nt = 0; nt < 2; ++nt) {
            int cl = wn * 32 + nt * 16 + lr;          // local col 0..63
            float s = sv[o0 + cl];
#pragma unroll
            for (int r = 0; r < 4; ++r) {
                int row = wm * 32 + mt * 16 + quad * 4 + r;
                float v = acc[mt][nt][r] * s + b2f(idb16[(long)(m0 + row) * C2 + o0 + cl]);
                sm.t.T[cl * 73 + row] = v;
            }
        }
    __syncthreads();
#pragma unroll
    for (int it = 0; it < 16; ++it) {
        int e = it * 256 + tid;
        int cc = e >> 6, nn = e & 63;
        long idx = (long)(o0 + cc) * NN + m0 + nn;
        float v = sm.t.T[cc * 73 + nn];
        if (f32o) ((float*)outp)[idx] = v;
        else      ((unsigned short*)outp)[idx] = f2b(v);
    }
}

extern "C" void kernel_launch(void* const* d_in, const int* in_sizes, int n_in,
                              void* d_out, int out_size, void* d_ws, size_t ws_size,
                              hipStream_t stream) {
    float* ws = (float*)d_ws;
    float* cvt   = ws;                          // C_END small fp32 params
    float* means = ws + 35200;                  // MSLOTS x 256
    float* svb   = means + MSLOTS * 256;        // 256
    float* als   = svb + 256;                   // 204800
    float* ald   = als + 204800;
    unsigned short* wb16  = (unsigned short*)(ald + 204800);  // 262144
    unsigned short* xT16  = wb16 + B_WEND;                    // 25600*128
    unsigned short* xf16  = xT16 + NN * 128;                  // 25600*256
    unsigned short* h16   = xf16 + NN * 256;                  // 25600*256
    unsigned short* idb16 = h16 + NN * 256;                   // 25600*256

    const unsigned short* xp = (const unsigned short*)d_in[0];

    dim3 b256(256);
    dim3 gmfma(NN / 64, C2 / 64);      // 400 x 4

    prep_kernel<<<400, b256, 0, stream>>>(
        xp, d_in[2], d_in[1], d_in[3], d_in[11],
        d_in[4], d_in[5], d_in[6], d_in[7], d_in[8], d_in[9], d_in[10],
        d_in[12], d_in[13], d_in[14], d_in[15],
        wb16, cvt, means, xT16);

    mfma_gemm_x2_kernel<<<gmfma, b256, 0, stream>>>(
        xT16, wb16 + B_WIN, wb16 + B_WID, xf16, idb16);

    for (int l = 0; l < 2; ++l) {
        gat_gemm_kernel<<<gmfma, b256, 0, stream>>>(
            xf16, wb16 + B_WGAT + l * 65536, h16,
            cvt + C_ASRC + l * 256, cvt + C_ADST + l * 256, als, ald);
        aggregate_kernel<<<NN / 8, b256, 0, stream>>>(h16, als, ald,
            cvt + C_BNA + l * 256, cvt + C_BNB + l * 256, xf16,
            (l == 1) ? means : nullptr);
    }

    se_kernel<<<1, b256, 0, stream>>>(wb16 + B_WOUT, means, cvt, svb);

    final_gemm_kernel<<<gmfma, b256, 0, stream>>>(
        xp, xf16, wb16 + B_WOUT, idb16, svb, d_out);
}

// Round 13
// 213.228 us; speedup vs baseline: 1.0223x; 1.0223x over previous
//
#include <hip/hip_runtime.h>

#define NN 25600      // nodes = 160*160
#define HH 160
#define WW 160
#define C2 256
#define MSLOTS 64     // colsum atomic spreading slots

// ---- bf16 weight pack offsets (ushorts) ----
#define B_WIN   0
#define B_WID   32768
#define B_WGAT  65536      // 2 layers x 65536
#define B_WOUT  196608
#define B_WEND  262144

// ---- small fp32 param offsets inside cvt (floats) ----
#define C_BNA   0          // 2x256 BN scale
#define C_BNB   512        // 2x256 BN shift (bias/mean folded)
#define C_ASRC  1024       // 2x256
#define C_ADST  1536       // 2x256
#define C_SEW1  2048       // 64x256
#define C_SEB1  18432      // 64
#define C_SEW2  18496      // 256x64
#define C_SEB2  34880      // 256
#define C_END   35136

typedef __attribute__((ext_vector_type(8))) short bfrag;   // 8 bf16 (4 VGPRs)
typedef __attribute__((ext_vector_type(4))) float ffrag;   // 4 fp32 acc

__device__ __forceinline__ float b2f(unsigned short u) {
    union { unsigned int ui; float f; } v; v.ui = ((unsigned int)u) << 16; return v.f;
}
__device__ __forceinline__ unsigned short f2b(float f) {
    union { float f; unsigned int u; } v; v.f = f;
    unsigned int u = v.u;
    unsigned int r = (u + 0x7FFFu + ((u >> 16) & 1u)) >> 16;
    return (unsigned short)r;
}
__device__ __forceinline__ float lo16f(unsigned int w) {
    union { unsigned int ui; float f; } v; v.ui = w << 16; return v.f;
}
__device__ __forceinline__ float hi16f(unsigned int w) {
    union { unsigned int ui; float f; } v; v.ui = w & 0xFFFF0000u; return v.f;
}
// Wave-uniform dtype probe on first 512 halfwords of x.
__device__ __forceinline__ bool probe_f32(const unsigned short* __restrict__ x) {
    int l = threadIdx.x & 63;
    bool wild = false;
#pragma unroll
    for (int i = 0; i < 8; ++i) {
        float v = b2f(x[l * 8 + i]);
        wild |= !(fabsf(v) < 1e6f);
    }
    return __any(wild);
}
__device__ __forceinline__ float ldf(const void* p, long i, bool f32) {
    return f32 ? ((const float*)p)[i] : b2f(((const unsigned short*)p)[i]);
}

// XCD-grouping swizzle for the 1600-block GEMM grids (1600 = 8 XCDs x 200):
// blocks with the same (bid & 7) land on one XCD chunk; consecutive work
// items w enumerate (panel, ntile) panel-major so the 4 N-tiles sharing an
// A-panel execute on the SAME XCD (L2-local A reuse). Bijective.
__device__ __forceinline__ void gemm_tile_ids(int bid, int& m0, int& o0) {
    int w = (bid & 7) * 200 + (bid >> 3);
    m0 = (w >> 2) * 64;
    o0 = (w & 3) * 64;
}

// Swizzled fragment pointer into an unpadded [64][64]-ushort LDS tile:
// chunk (16B) index is XOR'd with (row&7); matches the pre-swizzled
// global source used by the global_load_lds staging (rule: both sides).
__device__ __forceinline__ const bfrag* fragp(const unsigned short* buf, int row, int c8) {
    return (const bfrag*)(buf + row * 64 + ((c8 ^ (row & 7)) << 3));
}

// ---------------------------------------------------------------------------
// prep: pack weights bf16, fold BN, convert small params, zero means slots,
// AND transpose x -> bf16 [25600][128]. Grid = 400.
// ---------------------------------------------------------------------------
__global__ __launch_bounds__(256) void prep_kernel(
    const unsigned short* __restrict__ xp,
    const void* pwin, const void* pwid, const void* pwgat, const void* pwout,
    const void* pasrc, const void* padst, const void* pgbias,
    const void* pbng, const void* pbnb, const void* pbnm, const void* pbnv,
    const void* psew1, const void* pseb1, const void* psew2, const void* pseb2,
    unsigned short* __restrict__ wb, float* __restrict__ cvt,
    float* __restrict__ means, unsigned short* __restrict__ xT)
{
    __shared__ unsigned short T[64 * 136];
    const bool f32 = probe_f32(xp);
    const int tid = threadIdx.x;
    const int bid = blockIdx.x;
    const int gid = bid * 256 + tid;
    const int stride = gridDim.x * 256;

    for (int i = gid; i < MSLOTS * 256; i += stride) means[i] = 0.f;

    for (int i = gid; i < B_WEND; i += stride) {
        const void* s; int o;
        if      (i < B_WID)   { s = pwin;  o = i - B_WIN; }
        else if (i < B_WGAT)  { s = pwid;  o = i - B_WID; }
        else if (i < B_WOUT)  { s = pwgat; o = i - B_WGAT; }
        else                  { s = pwout; o = i - B_WOUT; }
        wb[i] = f32 ? f2b(((const float*)s)[o]) : ((const unsigned short*)s)[o];
    }
    for (int i = gid; i < 512; i += stride) {
        float sc = ldf(pbng, i, f32) * rsqrtf(ldf(pbnv, i, f32) + 1e-5f);
        cvt[C_BNA + i] = sc;
        cvt[C_BNB + i] = (ldf(pgbias, i, f32) - ldf(pbnm, i, f32)) * sc + ldf(pbnb, i, f32);
        cvt[C_ASRC + i] = ldf(pasrc, i, f32);
        cvt[C_ADST + i] = ldf(padst, i, f32);
    }
    for (int i = gid; i < 16384; i += stride) {
        cvt[C_SEW1 + i] = ldf(psew1, i, f32);
        cvt[C_SEW2 + i] = ldf(psew2, i, f32);
    }
    for (int i = gid; i < 64; i += stride)  cvt[C_SEB1 + i] = ldf(pseb1, i, f32);
    for (int i = gid; i < 256; i += stride) cvt[C_SEB2 + i] = ldf(pseb2, i, f32);

    // transpose slice: 64 nodes per block
    {
        const int n0 = bid * 64;
        const int nl = tid & 63;
#pragma unroll
        for (int i = 0; i < 32; ++i) {
            int c = i * 4 + (tid >> 6);
            long idx = (long)c * NN + n0 + nl;
            T[nl * 136 + c] = f32 ? f2b(((const float*)xp)[idx]) : xp[idx];
        }
        __syncthreads();
#pragma unroll
        for (int i = 0; i < 4; ++i) {
            int n = tid >> 2, c0 = (tid & 3) * 32 + i * 8;
            uint4 v = *(const uint4*)&T[n * 136 + c0];
            *(uint4*)(xT + (long)(n0 + n) * 128 + c0) = v;
        }
    }
}

// ---------------------------------------------------------------------------
// LDS layouts. GEMM staging tiles are UNPADDED [64][64] ushort (8 KB each):
// global_load_lds requires lane-linear destinations; bank conflicts on the
// fragment reads are broken by the XOR chunk swizzle (fragp / staging).
// C-staging keeps the padded 72-ushort rows (plain stores).
// ---------------------------------------------------------------------------
struct SmemC64 { unsigned short Cs[64 * 72]; };                      //  9216 B
struct SmemGu  { unsigned short As[4096], Bs[4096]; };               // 16384 B
union  SmemNu  { SmemGu g; SmemC64 c; };
struct SmemG2u { unsigned short As[4096], Bi[4096], Bd[4096]; };     // 24576 B
union  SmemXu  { SmemG2u g; SmemC64 c; };
struct SmemT   { float T[64 * 73]; };                                // 18688 B
union  SmemFu  { SmemGu g; SmemT t; };

// Stage one 64x64-ushort tile (64 rows x 64 cols of bf16) from global
// (row stride LDA ushorts, col offset k0) into LDS via global_load_lds,
// with pre-swizzled per-lane global chunk (q ^= row&7), linear LDS dest.
#define STAGE_TILE(DST, SRC, ROW0, LDA, K0)                                       \
    {                                                                             \
        _Pragma("unroll")                                                         \
        for (int ii = 0; ii < 2; ++ii) {                                          \
            int e = tid + ii * 256;                                               \
            int row = e >> 3;                                                     \
            int q = (e & 7) ^ (row & 7);                                          \
            __builtin_amdgcn_global_load_lds(                                     \
                (const unsigned int*)((SRC) + (long)((ROW0) + row) * (LDA) + (K0) + q * 8), \
                (unsigned int*)&(DST)[e * 8], 16, 0, 0);                          \
        }                                                                         \
    }

// ---------------------------------------------------------------------------
// MFMA GEMM (dual-B, K=128): xf16=A@Wi^T, idb16=A@Wd^T. Grid 1600, 256 thr.
// M-tile 64, BK=64 (2 k-steps). Staging via global_load_lds (async DMA).
// ---------------------------------------------------------------------------
__global__ __launch_bounds__(256) void mfma_gemm_x2_kernel(
    const unsigned short* __restrict__ A16,
    const unsigned short* __restrict__ Wi16,
    const unsigned short* __restrict__ Wd16,
    unsigned short* __restrict__ xf16,
    unsigned short* __restrict__ idb16)
{
    __shared__ SmemXu sm;
    const int tid = threadIdx.x;
    int m0, o0; gemm_tile_ids(blockIdx.x, m0, o0);
    const int lane = tid & 63, wv = tid >> 6;
    const int wm = wv >> 1, wn = wv & 1;
    const int lr = lane & 15, quad = lane >> 4;

    ffrag ai[2][2], ad[2][2];
#pragma unroll
    for (int mt = 0; mt < 2; ++mt)
#pragma unroll
        for (int nt = 0; nt < 2; ++nt) { ai[mt][nt] = (ffrag){0,0,0,0}; ad[mt][nt] = (ffrag){0,0,0,0}; }

    for (int k0 = 0; k0 < 128; k0 += 64) {
        STAGE_TILE(sm.g.As, A16,  m0, 128, k0)
        STAGE_TILE(sm.g.Bi, Wi16, o0, 128, k0)
        STAGE_TILE(sm.g.Bd, Wd16, o0, 128, k0)
        __syncthreads();   // drains vmcnt (DMA complete) before ds_reads
#pragma unroll
        for (int ks = 0; ks < 2; ++ks) {
            bfrag a[2], bi[2], bd[2];
#pragma unroll
            for (int mt = 0; mt < 2; ++mt)
                a[mt] = *fragp(sm.g.As, wm * 32 + mt * 16 + lr, ks * 4 + quad);
#pragma unroll
            for (int nt = 0; nt < 2; ++nt) {
                bi[nt] = *fragp(sm.g.Bi, wn * 32 + nt * 16 + lr, ks * 4 + quad);
                bd[nt] = *fragp(sm.g.Bd, wn * 32 + nt * 16 + lr, ks * 4 + quad);
            }
#pragma unroll
            for (int mt = 0; mt < 2; ++mt)
#pragma unroll
                for (int nt = 0; nt < 2; ++nt) {
                    ai[mt][nt] = __builtin_amdgcn_mfma_f32_16x16x32_bf16(a[mt], bi[nt], ai[mt][nt], 0, 0, 0);
                    ad[mt][nt] = __builtin_amdgcn_mfma_f32_16x16x32_bf16(a[mt], bd[nt], ad[mt][nt], 0, 0, 0);
                }
        }
        __syncthreads();
    }
    // epilogue 1: xf16
#pragma unroll
    for (int mt = 0; mt < 2; ++mt)
#pragma unroll
        for (int nt = 0; nt < 2; ++nt)
#pragma unroll
            for (int r = 0; r < 4; ++r)
                sm.c.Cs[(wm * 32 + mt * 16 + quad * 4 + r) * 72 + wn * 32 + nt * 16 + lr] = f2b(ai[mt][nt][r]);
    __syncthreads();
#pragma unroll
    for (int it = 0; it < 2; ++it) {
        int e = it * 256 + tid;
        int row = e >> 3, c8 = (e & 7) * 8;
        *(uint4*)(xf16 + (long)(m0 + row) * C2 + o0 + c8) = *(const uint4*)&sm.c.Cs[row * 72 + c8];
    }
    __syncthreads();
    // epilogue 2: idb16
#pragma unroll
    for (int mt = 0; mt < 2; ++mt)
#pragma unroll
        for (int nt = 0; nt < 2; ++nt)
#pragma unroll
            for (int r = 0; r < 4; ++r)
                sm.c.Cs[(wm * 32 + mt * 16 + quad * 4 + r) * 72 + wn * 32 + nt * 16 + lr] = f2b(ad[mt][nt][r]);
    __syncthreads();
#pragma unroll
    for (int it = 0; it < 2; ++it) {
        int e = it * 256 + tid;
        int row = e >> 3, c8 = (e & 7) * 8;
        *(uint4*)(idb16 + (long)(m0 + row) * C2 + o0 + c8) = *(const uint4*)&sm.c.Cs[row * 72 + c8];
    }
}

// ---------------------------------------------------------------------------
// GAT GEMM (K=256): h = xf@W^T + fused attention scores. Grid 1600, 256 thr.
// M-tile 64, BK=64 (4 k-steps). Staging via global_load_lds.
// ---------------------------------------------------------------------------
__global__ __launch_bounds__(256) void gat_gemm_kernel(
    const unsigned short* __restrict__ A16,
    const unsigned short* __restrict__ W16,
    unsigned short* __restrict__ Cout,
    const float* __restrict__ asrc, const float* __restrict__ adst,
    float* __restrict__ als_out, float* __restrict__ ald_out)
{
    __shared__ SmemNu sm;
    const int tid = threadIdx.x;
    int m0, o0; gemm_tile_ids(blockIdx.x, m0, o0);
    const int lane = tid & 63, wv = tid >> 6;
    const int wm = wv >> 1, wn = wv & 1;
    const int lr = lane & 15, quad = lane >> 4;

    ffrag acc[2][2];
#pragma unroll
    for (int mt = 0; mt < 2; ++mt)
#pragma unroll
        for (int nt = 0; nt < 2; ++nt) acc[mt][nt] = (ffrag){0,0,0,0};

    for (int k0 = 0; k0 < 256; k0 += 64) {
        STAGE_TILE(sm.g.As, A16, m0, C2, k0)
        STAGE_TILE(sm.g.Bs, W16, o0, C2, k0)
        __syncthreads();
#pragma unroll
        for (int ks = 0; ks < 2; ++ks) {
            bfrag a[2], b[2];
#pragma unroll
            for (int mt = 0; mt < 2; ++mt)
                a[mt] = *fragp(sm.g.As, wm * 32 + mt * 16 + lr, ks * 4 + quad);
#pragma unroll
            for (int nt = 0; nt < 2; ++nt)
                b[nt] = *fragp(sm.g.Bs, wn * 32 + nt * 16 + lr, ks * 4 + quad);
#pragma unroll
            for (int mt = 0; mt < 2; ++mt)
#pragma unroll
                for (int nt = 0; nt < 2; ++nt)
                    acc[mt][nt] = __builtin_amdgcn_mfma_f32_16x16x32_bf16(a[mt], b[nt], acc[mt][nt], 0, 0, 0);
        }
        __syncthreads();
    }
    // attention epilogue: wave covers head = (o0/32)+wn, d = nt*16+lr
    {
        const int head = (o0 >> 5) + wn;
        const float as0 = asrc[head * 32 + lr], as1 = asrc[head * 32 + 16 + lr];
        const float ad0 = adst[head * 32 + lr], ad1 = adst[head * 32 + 16 + lr];
#pragma unroll
        for (int mt = 0; mt < 2; ++mt)
#pragma unroll
            for (int r = 0; r < 4; ++r) {
                float ps = acc[mt][0][r] * as0 + acc[mt][1][r] * as1;
                float pd = acc[mt][0][r] * ad0 + acc[mt][1][r] * ad1;
#pragma unroll
                for (int sh = 1; sh < 16; sh <<= 1) {
                    ps += __shfl_xor(ps, sh);
                    pd += __shfl_xor(pd, sh);
                }
                if (lr == 0) {
                    int m = m0 + wm * 32 + mt * 16 + quad * 4 + r;
                    als_out[m * 8 + head] = ps;
                    ald_out[m * 8 + head] = pd;
                }
            }
    }
    // C store via LDS
#pragma unroll
    for (int mt = 0; mt < 2; ++mt)
#pragma unroll
        for (int nt = 0; nt < 2; ++nt)
#pragma unroll
            for (int r = 0; r < 4; ++r)
                sm.c.Cs[(wm * 32 + mt * 16 + quad * 4 + r) * 72 + wn * 32 + nt * 16 + lr] = f2b(acc[mt][nt][r]);
    __syncthreads();
#pragma unroll
    for (int it = 0; it < 2; ++it) {
        int e = it * 256 + tid;
        int row = e >> 3, c8 = (e & 7) * 8;
        *(uint4*)(Cout + (long)(m0 + row) * C2 + o0 + c8) = *(const uint4*)&sm.c.Cs[row * 72 + c8];
    }
}

// ---------------------------------------------------------------------------
// Aggregation: 8 nodes/block, 32 thr/node, 8 bf16 channels/thread. Grid 3200.
// Gather loads batched into registers (11x uint4) so vmcnt overlaps them.
// If means != nullptr (last hop): block-reduce colsum -> atomicAdd into one
// of MSLOTS slots (spread: ~50 serialized RMWs/address instead of 3200).
// ---------------------------------------------------------------------------
__global__ __launch_bounds__(256) void aggregate_kernel(
    const unsigned short* __restrict__ h16,
    const float* __restrict__ al_s,
    const float* __restrict__ al_d,
    const float* __restrict__ bnA,
    const float* __restrict__ bnB,
    unsigned short* __restrict__ xf16,
    float* __restrict__ means)
{
    const int SI[11] = { 1, 1, 1, 0, 0, -1, -1, -1, -2,  0, 0};
    const int SJ[11] = { 1, 0,-1, 1,-1,  1,  0, -1,  0, -2, 0};
    __shared__ float es[8][11][8];
    __shared__ float alpha[8][11][8];
    __shared__ float part[4][256];

    const int t = threadIdx.x;
    const int ln = t >> 5;
    const int l = t & 31;
    const int n = blockIdx.x * 8 + ln;
    const int i = n / WW, j = n % WW;

    for (int idx = t; idx < 704; idx += 256) {
        int lln = idx / 88, rem = idx - lln * 88;
        int k = rem >> 3, hh = rem & 7;
        int nn2 = blockIdx.x * 8 + lln;
        int ii = nn2 / WW, jj = nn2 - ii * WW;
        int si = ii + SI[k], sj = jj + SJ[k];
        bool okk = (si >= 0) & (si < HH) & (sj >= 0) & (sj < WW);
        es[lln][k][hh] = okk ? al_s[(si * WW + sj) * 8 + hh] : -1e30f;
    }
    __syncthreads();

    if (l < 8) {
        const int hd = l;
        const float ald = al_d[n * 8 + hd];
        float e[11];
        float mx = -1e30f;
#pragma unroll
        for (int k = 0; k < 11; ++k) {
            float v = es[ln][k][hd] + ald;
            v = v > 0.f ? v : 0.2f * v;
            e[k] = v;
            mx = fmaxf(mx, v);
        }
        float denom = 0.f;
#pragma unroll
        for (int k = 0; k < 11; ++k) {
            float p = __expf(e[k] - mx);
            e[k] = p;
            denom += p;
        }
        const float inv = 1.f / (denom + 1e-16f);
#pragma unroll
        for (int k = 0; k < 11; ++k) alpha[ln][k][hd] = e[k] * inv;
    }
    __syncthreads();

    const int c8 = l * 8;
    const int hd = l >> 2;
    int srcn[11];
#pragma unroll
    for (int k = 0; k < 11; ++k) {
        int si = i + SI[k], sj = j + SJ[k];
        bool ok = (si >= 0) & (si < HH) & (sj >= 0) & (sj < WW);
        srcn[k] = ok ? si * WW + sj : n;
    }
    // batched gather: all 12 loads issued before any consumption
    uint4 hv[11];
#pragma unroll
    for (int k = 0; k < 11; ++k)
        hv[k] = *(const uint4*)(h16 + (long)srcn[k] * C2 + c8);
    uint4 rv = *(const uint4*)(xf16 + (long)n * C2 + c8);

    float a0=0.f,a1=0.f,a2=0.f,a3=0.f,a4=0.f,a5=0.f,a6=0.f,a7=0.f;
#pragma unroll
    for (int k = 0; k < 11; ++k) {
        float al = alpha[ln][k][hd];
        a0 += al * lo16f(hv[k].x); a1 += al * hi16f(hv[k].x);
        a2 += al * lo16f(hv[k].y); a3 += al * hi16f(hv[k].y);
        a4 += al * lo16f(hv[k].z); a5 += al * hi16f(hv[k].z);
        a6 += al * lo16f(hv[k].w); a7 += al * hi16f(hv[k].w);
    }
    float acc8[8] = {a0,a1,a2,a3,a4,a5,a6,a7};
    float res[8] = {lo16f(rv.x),hi16f(rv.x),lo16f(rv.y),hi16f(rv.y),
                    lo16f(rv.z),hi16f(rv.z),lo16f(rv.w),hi16f(rv.w)};
    float out[8];
#pragma unroll
    for (int q = 0; q < 8; ++q) {
        int c = c8 + q;
        float g = acc8[q] * bnA[c] + bnB[c];
        out[q] = fmaxf(g, 0.f) + res[q];
    }
    ushort4 o16a, o16b;
    o16a.x = f2b(out[0]); o16a.y = f2b(out[1]); o16a.z = f2b(out[2]); o16a.w = f2b(out[3]);
    o16b.x = f2b(out[4]); o16b.y = f2b(out[5]); o16b.z = f2b(out[6]); o16b.w = f2b(out[7]);
    *(ushort4*)(xf16 + (long)n * C2 + c8)     = o16a;
    *(ushort4*)(xf16 + (long)n * C2 + c8 + 4) = o16b;

    // fused colsum for SE (last hop only), atomic-spread over MSLOTS slots
    if (means) {
        float s8[8];
#pragma unroll
        for (int q = 0; q < 8; ++q) {
            s8[q] = out[q];
            s8[q] += __shfl_xor(s8[q], 32);    // combine node pair within wave
        }
        const int wvi = t >> 6;
        if ((t & 63) < 32) {
#pragma unroll
            for (int q = 0; q < 8; ++q) part[wvi][c8 + q] = s8[q];
        }
        __syncthreads();
        {
            float v = part[0][t] + part[1][t] + part[2][t] + part[3][t];
            atomicAdd(&means[(blockIdx.x & (MSLOTS - 1)) * 256 + t], v);
        }
    }
}

// ---------------------------------------------------------------------------
// SE vector, computed ONCE: cs = slot-sum(means); mv = cs@Wout^T / N;
// hv = relu(W1@mv + b1); sv = sigmoid(W2@hv + b2). Grid 1 x 256 thr.
// ---------------------------------------------------------------------------
__global__ __launch_bounds__(256) void se_kernel(
    const unsigned short* __restrict__ W16,     // Wout bf16 [256][256]
    const float* __restrict__ means,
    const float* __restrict__ cvt,
    float* __restrict__ sv_out)
{
    __shared__ float cs[256], mv[256], hv[64];
    const int t = threadIdx.x;
    {
        float s0=0,s1=0,s2=0,s3=0,s4=0,s5=0,s6=0,s7=0;
#pragma unroll 2
        for (int sl = 0; sl < MSLOTS; sl += 8) {
            s0 += means[(sl+0)*256 + t]; s1 += means[(sl+1)*256 + t];
            s2 += means[(sl+2)*256 + t]; s3 += means[(sl+3)*256 + t];
            s4 += means[(sl+4)*256 + t]; s5 += means[(sl+5)*256 + t];
            s6 += means[(sl+6)*256 + t]; s7 += means[(sl+7)*256 + t];
        }
        cs[t] = ((s0+s1)+(s2+s3)) + ((s4+s5)+(s6+s7));
    }
    __syncthreads();
    {
        float s = 0.f;
        const unsigned short* wr = W16 + (long)t * C2;
#pragma unroll 4
        for (int k = 0; k < 256; k += 8) {
            uint4 w = *(const uint4*)(wr + k);
            s += cs[k]   * lo16f(w.x) + cs[k+1] * hi16f(w.x)
               + cs[k+2] * lo16f(w.y) + cs[k+3] * hi16f(w.y)
               + cs[k+4] * lo16f(w.z) + cs[k+5] * hi16f(w.z)
               + cs[k+6] * lo16f(w.w) + cs[k+7] * hi16f(w.w);
        }
        mv[t] = s * (1.0f / 25600.0f);
    }
    __syncthreads();
    if (t < 64) {
        const float* w1 = cvt + C_SEW1 + t * 256;
        float s = cvt[C_SEB1 + t];
        for (int cc = 0; cc < 256; cc += 4) {
            float4 w = *(const float4*)(w1 + cc);
            s += w.x * mv[cc] + w.y * mv[cc+1] + w.z * mv[cc+2] + w.w * mv[cc+3];
        }
        hv[t] = fmaxf(s, 0.f);
    }
    __syncthreads();
    {
        const float* w2 = cvt + C_SEW2 + t * 64;
        float s = cvt[C_SEB2 + t];
        for (int k = 0; k < 64; k += 4) {
            float4 w = *(const float4*)(w2 + k);
            s += w.x * hv[k] + w.y * hv[k+1] + w.z * hv[k+2] + w.w * hv[k+3];
        }
        sv_out[t] = 1.0f / (1.0f + __expf(-s));
    }
}

// ---------------------------------------------------------------------------
// Final: y-tile = xf@Wout^T (64x64 per block), out[c][n] = y*sv + idb,
// transposed store. Grid 1600, 256 thr. Staging via global_load_lds.
// ---------------------------------------------------------------------------
__global__ __launch_bounds__(256) void final_gemm_kernel(
    const unsigned short* __restrict__ x_probe,
    const unsigned short* __restrict__ A16,       // xf post-hop2
    const unsigned short* __restrict__ W16,       // Wout bf16 [256][256]
    const unsigned short* __restrict__ idb16,
    const float* __restrict__ sv,
    void* __restrict__ outp)
{
    __shared__ SmemFu sm;
    const bool f32o = probe_f32(x_probe);
    const int tid = threadIdx.x;
    int m0, o0; gemm_tile_ids(blockIdx.x, m0, o0);
    const int lane = tid & 63, wv = tid >> 6;
    const int wm = wv >> 1, wn = wv & 1;
    const int lr = lane & 15, quad = lane >> 4;

    ffrag acc[2][2];
#pragma unroll
    for (int mt = 0; mt < 2; ++mt)
#pragma unroll
        for (int nt = 0; nt < 2; ++nt) acc[mt][nt] = (ffrag){0,0,0,0};

    for (int k0 = 0; k0 < 256; k0 += 64) {
        STAGE_TILE(sm.g.As, A16, m0, C2, k0)
        STAGE_TILE(sm.g.Bs, W16, o0, C2, k0)
        __syncthreads();
#pragma unroll
        for (int ks = 0; ks < 2; ++ks) {
            bfrag a[2], b[2];
#pragma unroll
            for (int mt = 0; mt < 2; ++mt)
                a[mt] = *fragp(sm.g.As, wm * 32 + mt * 16 + lr, ks * 4 + quad);
#pragma unroll
            for (int nt = 0; nt < 2; ++nt)
                b[nt] = *fragp(sm.g.Bs, wn * 32 + nt * 16 + lr, ks * 4 + quad);
#pragma unroll
            for (int mt = 0; mt < 2; ++mt)
#pragma unroll
                for (int nt = 0; nt < 2; ++nt)
                    acc[mt][nt] = __builtin_amdgcn_mfma_f32_16x16x32_bf16(a[mt], b[nt], acc[mt][nt], 0, 0, 0);
        }
        __syncthreads();
    }

    // deposit y*sv + idb into T[col][row] (fp32), then coalesced transposed store
#pragma unroll
    for (int mt = 0; mt < 2; ++mt)
#pragma unroll
        for (int nt = 0; nt < 2; ++nt) {
            int cl = wn * 32 + nt * 16 + lr;          // local col 0..63
            float s = sv[o0 + cl];
#pragma unroll
            for (int r = 0; r < 4; ++r) {
                int row = wm * 32 + mt * 16 + quad * 4 + r;
                float v = acc[mt][nt][r] * s + b2f(idb16[(long)(m0 + row) * C2 + o0 + cl]);
                sm.t.T[cl * 73 + row] = v;
            }
        }
    __syncthreads();
#pragma unroll
    for (int it = 0; it < 16; ++it) {
        int e = it * 256 + tid;
        int cc = e >> 6, nn = e & 63;
        long idx = (long)(o0 + cc) * NN + m0 + nn;
        float v = sm.t.T[cc * 73 + nn];
        if (f32o) ((float*)outp)[idx] = v;
        else      ((unsigned short*)outp)[idx] = f2b(v);
    }
}

extern "C" void kernel_launch(void* const* d_in, const int* in_sizes, int n_in,
                              void* d_out, int out_size, void* d_ws, size_t ws_size,
                              hipStream_t stream) {
    float* ws = (float*)d_ws;
    float* cvt   = ws;                          // C_END small fp32 params
    float* means = ws + 35200;                  // MSLOTS x 256
    float* svb   = means + MSLOTS * 256;        // 256
    float* als   = svb + 256;                   // 204800
    float* ald   = als + 204800;
    unsigned short* wb16  = (unsigned short*)(ald + 204800);  // 262144
    unsigned short* xT16  = wb16 + B_WEND;                    // 25600*128
    unsigned short* xf16  = xT16 + NN * 128;                  // 25600*256
    unsigned short* h16   = xf16 + NN * 256;                  // 25600*256
    unsigned short* idb16 = h16 + NN * 256;                   // 25600*256

    const unsigned short* xp = (const unsigned short*)d_in[0];

    dim3 b256(256);

    prep_kernel<<<400, b256, 0, stream>>>(
        xp, d_in[2], d_in[1], d_in[3], d_in[11],
        d_in[4], d_in[5], d_in[6], d_in[7], d_in[8], d_in[9], d_in[10],
        d_in[12], d_in[13], d_in[14], d_in[15],
        wb16, cvt, means, xT16);

    mfma_gemm_x2_kernel<<<1600, b256, 0, stream>>>(
        xT16, wb16 + B_WIN, wb16 + B_WID, xf16, idb16);

    for (int l = 0; l < 2; ++l) {
        gat_gemm_kernel<<<1600, b256, 0, stream>>>(
            xf16, wb16 + B_WGAT + l * 65536, h16,
            cvt + C_ASRC + l * 256, cvt + C_ADST + l * 256, als, ald);
        aggregate_kernel<<<NN / 8, b256, 0, stream>>>(h16, als, ald,
            cvt + C_BNA + l * 256, cvt + C_BNB + l * 256, xf16,
            (l == 1) ? means : nullptr);
    }

    se_kernel<<<1, b256, 0, stream>>>(wb16 + B_WOUT, means, cvt, svb);

    final_gemm_kernel<<<1600, b256, 0, stream>>>(
        xp, xf16, wb16 + B_WOUT, idb16, svb, d_out);
}

// Round 14
// 205.990 us; speedup vs baseline: 1.0582x; 1.0351x over previous
//
#include <hip/hip_runtime.h>

#define NN 25600      // nodes = 160*160
#define HH 160
#define WW 160
#define C2 256
#define MSLOTS 64     // colsum atomic spreading slots

// ---- bf16 weight pack offsets (ushorts) ----
#define B_WIN   0
#define B_WID   32768
#define B_WGAT  65536      // 2 layers x 65536
#define B_WOUT  196608
#define B_WEND  262144

// ---- small fp32 param offsets inside cvt (floats) ----
#define C_BNA   0          // 2x256 BN scale
#define C_BNB   512        // 2x256 BN shift (bias/mean folded)
#define C_ASRC  1024       // 2x256
#define C_ADST  1536       // 2x256
#define C_SEW1  2048       // 64x256
#define C_SEB1  18432      // 64
#define C_SEW2  18496      // 256x64
#define C_SEB2  34880      // 256
#define C_END   35136

typedef __attribute__((ext_vector_type(8))) short bfrag;   // 8 bf16 (4 VGPRs)
typedef __attribute__((ext_vector_type(4))) float ffrag;   // 4 fp32 acc

__device__ __forceinline__ float b2f(unsigned short u) {
    union { unsigned int ui; float f; } v; v.ui = ((unsigned int)u) << 16; return v.f;
}
__device__ __forceinline__ unsigned short f2b(float f) {
    union { float f; unsigned int u; } v; v.f = f;
    unsigned int u = v.u;
    unsigned int r = (u + 0x7FFFu + ((u >> 16) & 1u)) >> 16;
    return (unsigned short)r;
}
__device__ __forceinline__ float lo16f(unsigned int w) {
    union { unsigned int ui; float f; } v; v.ui = w << 16; return v.f;
}
__device__ __forceinline__ float hi16f(unsigned int w) {
    union { unsigned int ui; float f; } v; v.ui = w & 0xFFFF0000u; return v.f;
}
// Wave-uniform dtype probe on first 512 halfwords of x.
__device__ __forceinline__ bool probe_f32(const unsigned short* __restrict__ x) {
    int l = threadIdx.x & 63;
    bool wild = false;
#pragma unroll
    for (int i = 0; i < 8; ++i) {
        float v = b2f(x[l * 8 + i]);
        wild |= !(fabsf(v) < 1e6f);
    }
    return __any(wild);
}
__device__ __forceinline__ float ldf(const void* p, long i, bool f32) {
    return f32 ? ((const float*)p)[i] : b2f(((const unsigned short*)p)[i]);
}

// XCD-grouping swizzle for the 1600-block GEMM grids (1600 = 8 XCDs x 200):
// neutral at this size (round 13) but free; helps if problem scales past L3.
__device__ __forceinline__ void gemm_tile_ids(int bid, int& m0, int& o0) {
    int w = (bid & 7) * 200 + (bid >> 3);
    m0 = (w >> 2) * 64;
    o0 = (w & 3) * 64;
}

// Swizzled fragment pointer into an unpadded [64][64]-ushort LDS tile:
// chunk (16B) index is XOR'd with (row&7); matches the pre-swizzled
// global source used by the global_load_lds staging (rule: both sides).
__device__ __forceinline__ const bfrag* fragp(const unsigned short* buf, int row, int c8) {
    return (const bfrag*)(buf + row * 64 + ((c8 ^ (row & 7)) << 3));
}

// ---------------------------------------------------------------------------
// prep: pack weights bf16, fold BN, convert small params, zero means slots,
// AND transpose x -> bf16 [25600][128]. Grid = 400.
// ---------------------------------------------------------------------------
__global__ __launch_bounds__(256) void prep_kernel(
    const unsigned short* __restrict__ xp,
    const void* pwin, const void* pwid, const void* pwgat, const void* pwout,
    const void* pasrc, const void* padst, const void* pgbias,
    const void* pbng, const void* pbnb, const void* pbnm, const void* pbnv,
    const void* psew1, const void* pseb1, const void* psew2, const void* pseb2,
    unsigned short* __restrict__ wb, float* __restrict__ cvt,
    float* __restrict__ means, unsigned short* __restrict__ xT)
{
    __shared__ unsigned short T[64 * 136];
    const bool f32 = probe_f32(xp);
    const int tid = threadIdx.x;
    const int bid = blockIdx.x;
    const int gid = bid * 256 + tid;
    const int stride = gridDim.x * 256;

    for (int i = gid; i < MSLOTS * 256; i += stride) means[i] = 0.f;

    for (int i = gid; i < B_WEND; i += stride) {
        const void* s; int o;
        if      (i < B_WID)   { s = pwin;  o = i - B_WIN; }
        else if (i < B_WGAT)  { s = pwid;  o = i - B_WID; }
        else if (i < B_WOUT)  { s = pwgat; o = i - B_WGAT; }
        else                  { s = pwout; o = i - B_WOUT; }
        wb[i] = f32 ? f2b(((const float*)s)[o]) : ((const unsigned short*)s)[o];
    }
    for (int i = gid; i < 512; i += stride) {
        float sc = ldf(pbng, i, f32) * rsqrtf(ldf(pbnv, i, f32) + 1e-5f);
        cvt[C_BNA + i] = sc;
        cvt[C_BNB + i] = (ldf(pgbias, i, f32) - ldf(pbnm, i, f32)) * sc + ldf(pbnb, i, f32);
        cvt[C_ASRC + i] = ldf(pasrc, i, f32);
        cvt[C_ADST + i] = ldf(padst, i, f32);
    }
    for (int i = gid; i < 16384; i += stride) {
        cvt[C_SEW1 + i] = ldf(psew1, i, f32);
        cvt[C_SEW2 + i] = ldf(psew2, i, f32);
    }
    for (int i = gid; i < 64; i += stride)  cvt[C_SEB1 + i] = ldf(pseb1, i, f32);
    for (int i = gid; i < 256; i += stride) cvt[C_SEB2 + i] = ldf(pseb2, i, f32);

    // transpose slice: 64 nodes per block
    {
        const int n0 = bid * 64;
        const int nl = tid & 63;
#pragma unroll
        for (int i = 0; i < 32; ++i) {
            int c = i * 4 + (tid >> 6);
            long idx = (long)c * NN + n0 + nl;
            T[nl * 136 + c] = f32 ? f2b(((const float*)xp)[idx]) : xp[idx];
        }
        __syncthreads();
#pragma unroll
        for (int i = 0; i < 4; ++i) {
            int n = tid >> 2, c0 = (tid & 3) * 32 + i * 8;
            uint4 v = *(const uint4*)&T[n * 136 + c0];
            *(uint4*)(xT + (long)(n0 + n) * 128 + c0) = v;
        }
    }
}

// ---------------------------------------------------------------------------
// LDS layouts. GEMM staging tiles are UNPADDED [64][64] ushort (8 KB each):
// global_load_lds requires lane-linear destinations; bank conflicts on the
// fragment reads are broken by the XOR chunk swizzle (fragp / staging).
// C-staging keeps the padded 72-ushort rows (plain stores).
// ---------------------------------------------------------------------------
struct SmemC64 { unsigned short Cs[64 * 72]; };                      //  9216 B
struct SmemGu  { unsigned short As[4096], Bs[4096]; };               // 16384 B
union  SmemNu  { SmemGu g; SmemC64 c; };
struct SmemG2u { unsigned short As[4096], Bi[4096], Bd[4096]; };     // 24576 B
union  SmemXu  { SmemG2u g; SmemC64 c; };
struct SmemT   { float T[64 * 73]; };                                // 18688 B
union  SmemFu  { SmemGu g; SmemT t; };

// Stage one 64x64-ushort tile (64 rows x 64 cols of bf16) from global
// (row stride LDA ushorts, col offset k0) into LDS via global_load_lds,
// with pre-swizzled per-lane global chunk (q ^= row&7), linear LDS dest.
#define STAGE_TILE(DST, SRC, ROW0, LDA, K0)                                       \
    {                                                                             \
        _Pragma("unroll")                                                         \
        for (int ii = 0; ii < 2; ++ii) {                                          \
            int e = tid + ii * 256;                                               \
            int row = e >> 3;                                                     \
            int q = (e & 7) ^ (row & 7);                                          \
            __builtin_amdgcn_global_load_lds(                                     \
                (const unsigned int*)((SRC) + (long)((ROW0) + row) * (LDA) + (K0) + q * 8), \
                (unsigned int*)&(DST)[e * 8], 16, 0, 0);                          \
        }                                                                         \
    }

// ---------------------------------------------------------------------------
// MFMA GEMM (dual-B, K=128): xf16=A@Wi^T, idb16=A@Wd^T. Grid 1600, 256 thr.
// M-tile 64, BK=64 (2 k-steps). Staging via global_load_lds (async DMA).
// ---------------------------------------------------------------------------
__global__ __launch_bounds__(256) void mfma_gemm_x2_kernel(
    const unsigned short* __restrict__ A16,
    const unsigned short* __restrict__ Wi16,
    const unsigned short* __restrict__ Wd16,
    unsigned short* __restrict__ xf16,
    unsigned short* __restrict__ idb16)
{
    __shared__ SmemXu sm;
    const int tid = threadIdx.x;
    int m0, o0; gemm_tile_ids(blockIdx.x, m0, o0);
    const int lane = tid & 63, wv = tid >> 6;
    const int wm = wv >> 1, wn = wv & 1;
    const int lr = lane & 15, quad = lane >> 4;

    ffrag ai[2][2], ad[2][2];
#pragma unroll
    for (int mt = 0; mt < 2; ++mt)
#pragma unroll
        for (int nt = 0; nt < 2; ++nt) { ai[mt][nt] = (ffrag){0,0,0,0}; ad[mt][nt] = (ffrag){0,0,0,0}; }

    for (int k0 = 0; k0 < 128; k0 += 64) {
        STAGE_TILE(sm.g.As, A16,  m0, 128, k0)
        STAGE_TILE(sm.g.Bi, Wi16, o0, 128, k0)
        STAGE_TILE(sm.g.Bd, Wd16, o0, 128, k0)
        __syncthreads();   // drains vmcnt (DMA complete) before ds_reads
#pragma unroll
        for (int ks = 0; ks < 2; ++ks) {
            bfrag a[2], bi[2], bd[2];
#pragma unroll
            for (int mt = 0; mt < 2; ++mt)
                a[mt] = *fragp(sm.g.As, wm * 32 + mt * 16 + lr, ks * 4 + quad);
#pragma unroll
            for (int nt = 0; nt < 2; ++nt) {
                bi[nt] = *fragp(sm.g.Bi, wn * 32 + nt * 16 + lr, ks * 4 + quad);
                bd[nt] = *fragp(sm.g.Bd, wn * 32 + nt * 16 + lr, ks * 4 + quad);
            }
#pragma unroll
            for (int mt = 0; mt < 2; ++mt)
#pragma unroll
                for (int nt = 0; nt < 2; ++nt) {
                    ai[mt][nt] = __builtin_amdgcn_mfma_f32_16x16x32_bf16(a[mt], bi[nt], ai[mt][nt], 0, 0, 0);
                    ad[mt][nt] = __builtin_amdgcn_mfma_f32_16x16x32_bf16(a[mt], bd[nt], ad[mt][nt], 0, 0, 0);
                }
        }
        __syncthreads();
    }
    // epilogue 1: xf16
#pragma unroll
    for (int mt = 0; mt < 2; ++mt)
#pragma unroll
        for (int nt = 0; nt < 2; ++nt)
#pragma unroll
            for (int r = 0; r < 4; ++r)
                sm.c.Cs[(wm * 32 + mt * 16 + quad * 4 + r) * 72 + wn * 32 + nt * 16 + lr] = f2b(ai[mt][nt][r]);
    __syncthreads();
#pragma unroll
    for (int it = 0; it < 2; ++it) {
        int e = it * 256 + tid;
        int row = e >> 3, c8 = (e & 7) * 8;
        *(uint4*)(xf16 + (long)(m0 + row) * C2 + o0 + c8) = *(const uint4*)&sm.c.Cs[row * 72 + c8];
    }
    __syncthreads();
    // epilogue 2: idb16
#pragma unroll
    for (int mt = 0; mt < 2; ++mt)
#pragma unroll
        for (int nt = 0; nt < 2; ++nt)
#pragma unroll
            for (int r = 0; r < 4; ++r)
                sm.c.Cs[(wm * 32 + mt * 16 + quad * 4 + r) * 72 + wn * 32 + nt * 16 + lr] = f2b(ad[mt][nt][r]);
    __syncthreads();
#pragma unroll
    for (int it = 0; it < 2; ++it) {
        int e = it * 256 + tid;
        int row = e >> 3, c8 = (e & 7) * 8;
        *(uint4*)(idb16 + (long)(m0 + row) * C2 + o0 + c8) = *(const uint4*)&sm.c.Cs[row * 72 + c8];
    }
}

// ---------------------------------------------------------------------------
// GAT GEMM (K=256): h = xf@W^T + fused attention scores. Grid 1600, 256 thr.
// M-tile 64, BK=64 (4 k-steps). Staging via global_load_lds.
// ---------------------------------------------------------------------------
__global__ __launch_bounds__(256) void gat_gemm_kernel(
    const unsigned short* __restrict__ A16,
    const unsigned short* __restrict__ W16,
    unsigned short* __restrict__ Cout,
    const float* __restrict__ asrc, const float* __restrict__ adst,
    float* __restrict__ als_out, float* __restrict__ ald_out)
{
    __shared__ SmemNu sm;
    const int tid = threadIdx.x;
    int m0, o0; gemm_tile_ids(blockIdx.x, m0, o0);
    const int lane = tid & 63, wv = tid >> 6;
    const int wm = wv >> 1, wn = wv & 1;
    const int lr = lane & 15, quad = lane >> 4;

    ffrag acc[2][2];
#pragma unroll
    for (int mt = 0; mt < 2; ++mt)
#pragma unroll
        for (int nt = 0; nt < 2; ++nt) acc[mt][nt] = (ffrag){0,0,0,0};

    for (int k0 = 0; k0 < 256; k0 += 64) {
        STAGE_TILE(sm.g.As, A16, m0, C2, k0)
        STAGE_TILE(sm.g.Bs, W16, o0, C2, k0)
        __syncthreads();
#pragma unroll
        for (int ks = 0; ks < 2; ++ks) {
            bfrag a[2], b[2];
#pragma unroll
            for (int mt = 0; mt < 2; ++mt)
                a[mt] = *fragp(sm.g.As, wm * 32 + mt * 16 + lr, ks * 4 + quad);
#pragma unroll
            for (int nt = 0; nt < 2; ++nt)
                b[nt] = *fragp(sm.g.Bs, wn * 32 + nt * 16 + lr, ks * 4 + quad);
#pragma unroll
            for (int mt = 0; mt < 2; ++mt)
#pragma unroll
                for (int nt = 0; nt < 2; ++nt)
                    acc[mt][nt] = __builtin_amdgcn_mfma_f32_16x16x32_bf16(a[mt], b[nt], acc[mt][nt], 0, 0, 0);
        }
        __syncthreads();
    }
    // attention epilogue: wave covers head = (o0/32)+wn, d = nt*16+lr
    {
        const int head = (o0 >> 5) + wn;
        const float as0 = asrc[head * 32 + lr], as1 = asrc[head * 32 + 16 + lr];
        const float ad0 = adst[head * 32 + lr], ad1 = adst[head * 32 + 16 + lr];
#pragma unroll
        for (int mt = 0; mt < 2; ++mt)
#pragma unroll
            for (int r = 0; r < 4; ++r) {
                float ps = acc[mt][0][r] * as0 + acc[mt][1][r] * as1;
                float pd = acc[mt][0][r] * ad0 + acc[mt][1][r] * ad1;
#pragma unroll
                for (int sh = 1; sh < 16; sh <<= 1) {
                    ps += __shfl_xor(ps, sh);
                    pd += __shfl_xor(pd, sh);
                }
                if (lr == 0) {
                    int m = m0 + wm * 32 + mt * 16 + quad * 4 + r;
                    als_out[m * 8 + head] = ps;
                    ald_out[m * 8 + head] = pd;
                }
            }
    }
    // C store via LDS
#pragma unroll
    for (int mt = 0; mt < 2; ++mt)
#pragma unroll
        for (int nt = 0; nt < 2; ++nt)
#pragma unroll
            for (int r = 0; r < 4; ++r)
                sm.c.Cs[(wm * 32 + mt * 16 + quad * 4 + r) * 72 + wn * 32 + nt * 16 + lr] = f2b(acc[mt][nt][r]);
    __syncthreads();
#pragma unroll
    for (int it = 0; it < 2; ++it) {
        int e = it * 256 + tid;
        int row = e >> 3, c8 = (e & 7) * 8;
        *(uint4*)(Cout + (long)(m0 + row) * C2 + o0 + c8) = *(const uint4*)&sm.c.Cs[row * 72 + c8];
    }
}

// ---------------------------------------------------------------------------
// Aggregation: 8 nodes/block, 32 thr/node, 8 bf16 channels/thread. Grid 3200.
// BARRIER-FREE main path: each thread computes its own (node, head) softmax
// in registers (11 scalar al_s loads, wave-broadcast across the 4 threads
// sharing a head) — removes the es/alpha LDS phases and both barriers.
// If means != nullptr (last hop): block-reduce colsum -> atomicAdd into one
// of MSLOTS slots (spread: ~50 serialized RMWs/address instead of 3200).
// ---------------------------------------------------------------------------
__global__ __launch_bounds__(256) void aggregate_kernel(
    const unsigned short* __restrict__ h16,
    const float* __restrict__ al_s,
    const float* __restrict__ al_d,
    const float* __restrict__ bnA,
    const float* __restrict__ bnB,
    unsigned short* __restrict__ xf16,
    float* __restrict__ means)
{
    const int SI[11] = { 1, 1, 1, 0, 0, -1, -1, -1, -2,  0, 0};
    const int SJ[11] = { 1, 0,-1, 1,-1,  1,  0, -1,  0, -2, 0};
    __shared__ float part[4][256];

    const int t = threadIdx.x;
    const int ln = t >> 5;
    const int l = t & 31;
    const int n = blockIdx.x * 8 + ln;
    const int i = n / WW, j = n % WW;
    const int c8 = l * 8;
    const int hd = l >> 2;

    // neighbor indices + validity
    int srcn[11]; bool okm[11];
#pragma unroll
    for (int k = 0; k < 11; ++k) {
        int si = i + SI[k], sj = j + SJ[k];
        bool ok = (si >= 0) & (si < HH) & (sj >= 0) & (sj < WW);
        okm[k] = ok;
        srcn[k] = ok ? si * WW + sj : n;
    }

    // per-thread softmax over incoming edges for head hd (4x redundant within
    // wave -> loads broadcast; no LDS, no barriers)
    float e[11];
    {
        const float ald = al_d[n * 8 + hd];
        float mx = -1e30f;
#pragma unroll
        for (int k = 0; k < 11; ++k) {
            float s = al_s[(long)srcn[k] * 8 + hd];
            float v = s + ald;
            v = v > 0.f ? v : 0.2f * v;
            v = okm[k] ? v : -1e30f;
            e[k] = v;
            mx = fmaxf(mx, v);
        }
        float denom = 0.f;
#pragma unroll
        for (int k = 0; k < 11; ++k) {
            float p = __expf(e[k] - mx);
            e[k] = p;
            denom += p;
        }
        const float inv = 1.f / (denom + 1e-16f);
#pragma unroll
        for (int k = 0; k < 11; ++k) e[k] *= inv;   // alpha
    }

    // batched gather: all 12 uint4 loads issued before any consumption
    uint4 hv[11];
#pragma unroll
    for (int k = 0; k < 11; ++k)
        hv[k] = *(const uint4*)(h16 + (long)srcn[k] * C2 + c8);
    uint4 rv = *(const uint4*)(xf16 + (long)n * C2 + c8);

    float a0=0.f,a1=0.f,a2=0.f,a3=0.f,a4=0.f,a5=0.f,a6=0.f,a7=0.f;
#pragma unroll
    for (int k = 0; k < 11; ++k) {
        float al = e[k];
        a0 += al * lo16f(hv[k].x); a1 += al * hi16f(hv[k].x);
        a2 += al * lo16f(hv[k].y); a3 += al * hi16f(hv[k].y);
        a4 += al * lo16f(hv[k].z); a5 += al * hi16f(hv[k].z);
        a6 += al * lo16f(hv[k].w); a7 += al * hi16f(hv[k].w);
    }
    float acc8[8] = {a0,a1,a2,a3,a4,a5,a6,a7};
    float res[8] = {lo16f(rv.x),hi16f(rv.x),lo16f(rv.y),hi16f(rv.y),
                    lo16f(rv.z),hi16f(rv.z),lo16f(rv.w),hi16f(rv.w)};
    float out[8];
#pragma unroll
    for (int q = 0; q < 8; ++q) {
        int c = c8 + q;
        float g = acc8[q] * bnA[c] + bnB[c];
        out[q] = fmaxf(g, 0.f) + res[q];
    }
    ushort4 o16a, o16b;
    o16a.x = f2b(out[0]); o16a.y = f2b(out[1]); o16a.z = f2b(out[2]); o16a.w = f2b(out[3]);
    o16b.x = f2b(out[4]); o16b.y = f2b(out[5]); o16b.z = f2b(out[6]); o16b.w = f2b(out[7]);
    *(ushort4*)(xf16 + (long)n * C2 + c8)     = o16a;
    *(ushort4*)(xf16 + (long)n * C2 + c8 + 4) = o16b;

    // fused colsum for SE (last hop only), atomic-spread over MSLOTS slots
    if (means) {
        float s8[8];
#pragma unroll
        for (int q = 0; q < 8; ++q) {
            s8[q] = out[q];
            s8[q] += __shfl_xor(s8[q], 32);    // combine node pair within wave
        }
        const int wvi = t >> 6;
        if ((t & 63) < 32) {
#pragma unroll
            for (int q = 0; q < 8; ++q) part[wvi][c8 + q] = s8[q];
        }
        __syncthreads();
        {
            float v = part[0][t] + part[1][t] + part[2][t] + part[3][t];
            atomicAdd(&means[(blockIdx.x & (MSLOTS - 1)) * 256 + t], v);
        }
    }
}

// ---------------------------------------------------------------------------
// SE vector, computed ONCE: cs = slot-sum(means); mv = cs@Wout^T / N;
// hv = relu(W1@mv + b1); sv = sigmoid(W2@hv + b2). Grid 1 x 256 thr.
// ---------------------------------------------------------------------------
__global__ __launch_bounds__(256) void se_kernel(
    const unsigned short* __restrict__ W16,     // Wout bf16 [256][256]
    const float* __restrict__ means,
    const float* __restrict__ cvt,
    float* __restrict__ sv_out)
{
    __shared__ float cs[256], mv[256], hv[64];
    const int t = threadIdx.x;
    {
        float s0=0,s1=0,s2=0,s3=0,s4=0,s5=0,s6=0,s7=0;
#pragma unroll 2
        for (int sl = 0; sl < MSLOTS; sl += 8) {
            s0 += means[(sl+0)*256 + t]; s1 += means[(sl+1)*256 + t];
            s2 += means[(sl+2)*256 + t]; s3 += means[(sl+3)*256 + t];
            s4 += means[(sl+4)*256 + t]; s5 += means[(sl+5)*256 + t];
            s6 += means[(sl+6)*256 + t]; s7 += means[(sl+7)*256 + t];
        }
        cs[t] = ((s0+s1)+(s2+s3)) + ((s4+s5)+(s6+s7));
    }
    __syncthreads();
    {
        float s = 0.f;
        const unsigned short* wr = W16 + (long)t * C2;
#pragma unroll 4
        for (int k = 0; k < 256; k += 8) {
            uint4 w = *(const uint4*)(wr + k);
            s += cs[k]   * lo16f(w.x) + cs[k+1] * hi16f(w.x)
               + cs[k+2] * lo16f(w.y) + cs[k+3] * hi16f(w.y)
               + cs[k+4] * lo16f(w.z) + cs[k+5] * hi16f(w.z)
               + cs[k+6] * lo16f(w.w) + cs[k+7] * hi16f(w.w);
        }
        mv[t] = s * (1.0f / 25600.0f);
    }
    __syncthreads();
    if (t < 64) {
        const float* w1 = cvt + C_SEW1 + t * 256;
        float s = cvt[C_SEB1 + t];
        for (int cc = 0; cc < 256; cc += 4) {
            float4 w = *(const float4*)(w1 + cc);
            s += w.x * mv[cc] + w.y * mv[cc+1] + w.z * mv[cc+2] + w.w * mv[cc+3];
        }
        hv[t] = fmaxf(s, 0.f);
    }
    __syncthreads();
    {
        const float* w2 = cvt + C_SEW2 + t * 64;
        float s = cvt[C_SEB2 + t];
        for (int k = 0; k < 64; k += 4) {
            float4 w = *(const float4*)(w2 + k);
            s += w.x * hv[k] + w.y * hv[k+1] + w.z * hv[k+2] + w.w * hv[k+3];
        }
        sv_out[t] = 1.0f / (1.0f + __expf(-s));
    }
}

// ---------------------------------------------------------------------------
// Final: y-tile = xf@Wout^T (64x64 per block), out[c][n] = y*sv + idb,
// transposed store. Grid 1600, 256 thr. Staging via global_load_lds.
// ---------------------------------------------------------------------------
__global__ __launch_bounds__(256) void final_gemm_kernel(
    const unsigned short* __restrict__ x_probe,
    const unsigned short* __restrict__ A16,       // xf post-hop2
    const unsigned short* __restrict__ W16,       // Wout bf16 [256][256]
    const unsigned short* __restrict__ idb16,
    const float* __restrict__ sv,
    void* __restrict__ outp)
{
    __shared__ SmemFu sm;
    const bool f32o = probe_f32(x_probe);
    const int tid = threadIdx.x;
    int m0, o0; gemm_tile_ids(blockIdx.x, m0, o0);
    const int lane = tid & 63, wv = tid >> 6;
    const int wm = wv >> 1, wn = wv & 1;
    const int lr = lane & 15, quad = lane >> 4;

    ffrag acc[2][2];
#pragma unroll
    for (int mt = 0; mt < 2; ++mt)
#pragma unroll
        for (int nt = 0; nt < 2; ++nt) acc[mt][nt] = (ffrag){0,0,0,0};

    for (int k0 = 0; k0 < 256; k0 += 64) {
        STAGE_TILE(sm.g.As, A16, m0, C2, k0)
        STAGE_TILE(sm.g.Bs, W16, o0, C2, k0)
        __syncthreads();
#pragma unroll
        for (int ks = 0; ks < 2; ++ks) {
            bfrag a[2], b[2];
#pragma unroll
            for (int mt = 0; mt < 2; ++mt)
                a[mt] = *fragp(sm.g.As, wm * 32 + mt * 16 + lr, ks * 4 + quad);
#pragma unroll
            for (int nt = 0; nt < 2; ++nt)
                b[nt] = *fragp(sm.g.Bs, wn * 32 + nt * 16 + lr, ks * 4 + quad);
#pragma unroll
            for (int mt = 0; mt < 2; ++mt)
#pragma unroll
                for (int nt = 0; nt < 2; ++nt)
                    acc[mt][nt] = __builtin_amdgcn_mfma_f32_16x16x32_bf16(a[mt], b[nt], acc[mt][nt], 0, 0, 0);
        }
        __syncthreads();
    }

    // deposit y*sv + idb into T[col][row] (fp32), then coalesced transposed store
#pragma unroll
    for (int mt = 0; mt < 2; ++mt)
#pragma unroll
        for (int nt = 0; nt < 2; ++nt) {
            int cl = wn * 32 + nt * 16 + lr;          // local col 0..63
            float s = sv[o0 + cl];
#pragma unroll
            for (int r = 0; r < 4; ++r) {
                int row = wm * 32 + mt * 16 + quad * 4 + r;
                float v = acc[mt][nt][r] * s + b2f(idb16[(long)(m0 + row) * C2 + o0 + cl]);
                sm.t.T[cl * 73 + row] = v;
            }
        }
    __syncthreads();
#pragma unroll
    for (int it = 0; it < 16; ++it) {
        int e = it * 256 + tid;
        int cc = e >> 6, nn = e & 63;
        long idx = (long)(o0 + cc) * NN + m0 + nn;
        float v = sm.t.T[cc * 73 + nn];
        if (f32o) ((float*)outp)[idx] = v;
        else      ((unsigned short*)outp)[idx] = f2b(v);
    }
}

extern "C" void kernel_launch(void* const* d_in, const int* in_sizes, int n_in,
                              void* d_out, int out_size, void* d_ws, size_t ws_size,
                              hipStream_t stream) {
    float* ws = (float*)d_ws;
    float* cvt   = ws;                          // C_END small fp32 params
    float* means = ws + 35200;                  // MSLOTS x 256
    float* svb   = means + MSLOTS * 256;        // 256
    float* als   = svb + 256;                   // 204800
    float* ald   = als + 204800;
    unsigned short* wb16  = (unsigned short*)(ald + 204800);  // 262144
    unsigned short* xT16  = wb16 + B_WEND;                    // 25600*128
    unsigned short* xf16  = xT16 + NN * 128;                  // 25600*256
    unsigned short* h16   = xf16 + NN * 256;                  // 25600*256
    unsigned short* idb16 = h16 + NN * 256;                   // 25600*256

    const unsigned short* xp = (const unsigned short*)d_in[0];

    dim3 b256(256);

    prep_kernel<<<400, b256, 0, stream>>>(
        xp, d_in[2], d_in[1], d_in[3], d_in[11],
        d_in[4], d_in[5], d_in[6], d_in[7], d_in[8], d_in[9], d_in[10],
        d_in[12], d_in[13], d_in[14], d_in[15],
        wb16, cvt, means, xT16);

    mfma_gemm_x2_kernel<<<1600, b256, 0, stream>>>(
        xT16, wb16 + B_WIN, wb16 + B_WID, xf16, idb16);

    for (int l = 0; l < 2; ++l) {
        gat_gemm_kernel<<<1600, b256, 0, stream>>>(
            xf16, wb16 + B_WGAT + l * 65536, h16,
            cvt + C_ASRC + l * 256, cvt + C_ADST + l * 256, als, ald);
        aggregate_kernel<<<NN / 8, b256, 0, stream>>>(h16, als, ald,
            cvt + C_BNA + l * 256, cvt + C_BNB + l * 256, xf16,
            (l == 1) ? means : nullptr);
    }

    se_kernel<<<1, b256, 0, stream>>>(wb16 + B_WOUT, means, cvt, svb);

    final_gemm_kernel<<<1600, b256, 0, stream>>>(
        xp, xf16, wb16 + B_WOUT, idb16, svb, d_out);
}

// Round 15
// 201.898 us; speedup vs baseline: 1.0797x; 1.0203x over previous
//
#include <hip/hip_runtime.h>

#define NN 25600      // nodes = 160*160
#define HH 160
#define WW 160
#define C2 256
#define MSLOTS 64     // colsum atomic spreading slots

// ---- bf16 weight pack offsets (ushorts) ----
#define B_WIN   0
#define B_WID   32768
#define B_WGAT  65536      // 2 layers x 65536
#define B_WOUT  196608
#define B_WEND  262144

// ---- small fp32 param offsets inside cvt (floats) ----
#define C_BNA   0          // 2x256 BN scale
#define C_BNB   512        // 2x256 BN shift (bias/mean folded)
#define C_ASRC  1024       // 2x256
#define C_ADST  1536       // 2x256
#define C_SEW1  2048       // 64x256
#define C_SEB1  18432      // 64
#define C_SEW2  18496      // 256x64
#define C_SEB2  34880      // 256
#define C_END   35136

typedef __attribute__((ext_vector_type(8))) short bfrag;   // 8 bf16 (4 VGPRs)
typedef __attribute__((ext_vector_type(4))) float ffrag;   // 4 fp32 acc

__device__ __forceinline__ float b2f(unsigned short u) {
    union { unsigned int ui; float f; } v; v.ui = ((unsigned int)u) << 16; return v.f;
}
__device__ __forceinline__ unsigned short f2b(float f) {
    union { float f; unsigned int u; } v; v.f = f;
    unsigned int u = v.u;
    unsigned int r = (u + 0x7FFFu + ((u >> 16) & 1u)) >> 16;
    return (unsigned short)r;
}
__device__ __forceinline__ float lo16f(unsigned int w) {
    union { unsigned int ui; float f; } v; v.ui = w << 16; return v.f;
}
__device__ __forceinline__ float hi16f(unsigned int w) {
    union { unsigned int ui; float f; } v; v.ui = w & 0xFFFF0000u; return v.f;
}
// Wave-uniform dtype probe on first 512 halfwords of x.
__device__ __forceinline__ bool probe_f32(const unsigned short* __restrict__ x) {
    int l = threadIdx.x & 63;
    bool wild = false;
#pragma unroll
    for (int i = 0; i < 8; ++i) {
        float v = b2f(x[l * 8 + i]);
        wild |= !(fabsf(v) < 1e6f);
    }
    return __any(wild);
}
__device__ __forceinline__ float ldf(const void* p, long i, bool f32) {
    return f32 ? ((const float*)p)[i] : b2f(((const unsigned short*)p)[i]);
}

// XCD-grouping swizzle for the 1600-block GEMM grids (1600 = 8 XCDs x 200):
// neutral at this size (round 13) but free; helps if problem scales past L3.
__device__ __forceinline__ void gemm_tile_ids(int bid, int& m0, int& o0) {
    int w = (bid & 7) * 200 + (bid >> 3);
    m0 = (w >> 2) * 64;
    o0 = (w & 3) * 64;
}

// Swizzled fragment pointer into an unpadded [64][64]-ushort LDS tile:
// chunk (16B) index is XOR'd with (row&7); matches the pre-swizzled
// global source used by the global_load_lds staging (rule: both sides).
__device__ __forceinline__ const bfrag* fragp(const unsigned short* buf, int row, int c8) {
    return (const bfrag*)(buf + row * 64 + ((c8 ^ (row & 7)) << 3));
}

// ---------------------------------------------------------------------------
// prep: pack weights bf16, fold BN, convert small params, zero means slots,
// AND transpose x -> bf16 [25600][128]. Grid = 400.
// ---------------------------------------------------------------------------
__global__ __launch_bounds__(256) void prep_kernel(
    const unsigned short* __restrict__ xp,
    const void* pwin, const void* pwid, const void* pwgat, const void* pwout,
    const void* pasrc, const void* padst, const void* pgbias,
    const void* pbng, const void* pbnb, const void* pbnm, const void* pbnv,
    const void* psew1, const void* pseb1, const void* psew2, const void* pseb2,
    unsigned short* __restrict__ wb, float* __restrict__ cvt,
    float* __restrict__ means, unsigned short* __restrict__ xT)
{
    __shared__ unsigned short T[64 * 136];
    const bool f32 = probe_f32(xp);
    const int tid = threadIdx.x;
    const int bid = blockIdx.x;
    const int gid = bid * 256 + tid;
    const int stride = gridDim.x * 256;

    for (int i = gid; i < MSLOTS * 256; i += stride) means[i] = 0.f;

    for (int i = gid; i < B_WEND; i += stride) {
        const void* s; int o;
        if      (i < B_WID)   { s = pwin;  o = i - B_WIN; }
        else if (i < B_WGAT)  { s = pwid;  o = i - B_WID; }
        else if (i < B_WOUT)  { s = pwgat; o = i - B_WGAT; }
        else                  { s = pwout; o = i - B_WOUT; }
        wb[i] = f32 ? f2b(((const float*)s)[o]) : ((const unsigned short*)s)[o];
    }
    for (int i = gid; i < 512; i += stride) {
        float sc = ldf(pbng, i, f32) * rsqrtf(ldf(pbnv, i, f32) + 1e-5f);
        cvt[C_BNA + i] = sc;
        cvt[C_BNB + i] = (ldf(pgbias, i, f32) - ldf(pbnm, i, f32)) * sc + ldf(pbnb, i, f32);
        cvt[C_ASRC + i] = ldf(pasrc, i, f32);
        cvt[C_ADST + i] = ldf(padst, i, f32);
    }
    for (int i = gid; i < 16384; i += stride) {
        cvt[C_SEW1 + i] = ldf(psew1, i, f32);
        cvt[C_SEW2 + i] = ldf(psew2, i, f32);
    }
    for (int i = gid; i < 64; i += stride)  cvt[C_SEB1 + i] = ldf(pseb1, i, f32);
    for (int i = gid; i < 256; i += stride) cvt[C_SEB2 + i] = ldf(pseb2, i, f32);

    // transpose slice: 64 nodes per block
    {
        const int n0 = bid * 64;
        const int nl = tid & 63;
#pragma unroll
        for (int i = 0; i < 32; ++i) {
            int c = i * 4 + (tid >> 6);
            long idx = (long)c * NN + n0 + nl;
            T[nl * 136 + c] = f32 ? f2b(((const float*)xp)[idx]) : xp[idx];
        }
        __syncthreads();
#pragma unroll
        for (int i = 0; i < 4; ++i) {
            int n = tid >> 2, c0 = (tid & 3) * 32 + i * 8;
            uint4 v = *(const uint4*)&T[n * 136 + c0];
            *(uint4*)(xT + (long)(n0 + n) * 128 + c0) = v;
        }
    }
}

// ---------------------------------------------------------------------------
// LDS layouts. GEMM staging tiles are UNPADDED [64][64] ushort (8 KB each):
// global_load_lds requires lane-linear destinations; bank conflicts on the
// fragment reads are broken by the XOR chunk swizzle (fragp / staging).
// C-staging keeps the padded 72-ushort rows (plain stores).
// ---------------------------------------------------------------------------
struct SmemC64 { unsigned short Cs[64 * 72]; };                      //  9216 B
struct SmemGu  { unsigned short As[4096], Bs[4096]; };               // 16384 B
union  SmemNu  { SmemGu g; SmemC64 c; };
struct SmemT   { float T[64 * 73]; };                                // 18688 B
union  SmemFu  { SmemGu g; SmemT t; };

// Stage one 64x64-ushort tile (64 rows x 64 cols of bf16) from global
// (row stride LDA ushorts, col offset k0) into LDS via global_load_lds,
// with pre-swizzled per-lane global chunk (q ^= row&7), linear LDS dest.
#define STAGE_TILE(DST, SRC, ROW0, LDA, K0)                                       \
    {                                                                             \
        _Pragma("unroll")                                                         \
        for (int ii = 0; ii < 2; ++ii) {                                          \
            int e = tid + ii * 256;                                               \
            int row = e >> 3;                                                     \
            int q = (e & 7) ^ (row & 7);                                          \
            __builtin_amdgcn_global_load_lds(                                     \
                (const unsigned int*)((SRC) + (long)((ROW0) + row) * (LDA) + (K0) + q * 8), \
                (unsigned int*)&(DST)[e * 8], 16, 0, 0);                          \
        }                                                                         \
    }

// ---------------------------------------------------------------------------
// MFMA GEMM (K=128): xf16 = xT@Win^T. Grid 1600, 256 thr.
// M-tile 64, BK=64 (2 k-steps). (idb is now recomputed in final_gemm.)
// ---------------------------------------------------------------------------
__global__ __launch_bounds__(256) void mfma_gemm_kernel(
    const unsigned short* __restrict__ A16,
    const unsigned short* __restrict__ Wi16,
    unsigned short* __restrict__ xf16)
{
    __shared__ SmemNu sm;
    const int tid = threadIdx.x;
    int m0, o0; gemm_tile_ids(blockIdx.x, m0, o0);
    const int lane = tid & 63, wv = tid >> 6;
    const int wm = wv >> 1, wn = wv & 1;
    const int lr = lane & 15, quad = lane >> 4;

    ffrag ai[2][2];
#pragma unroll
    for (int mt = 0; mt < 2; ++mt)
#pragma unroll
        for (int nt = 0; nt < 2; ++nt) ai[mt][nt] = (ffrag){0,0,0,0};

    for (int k0 = 0; k0 < 128; k0 += 64) {
        STAGE_TILE(sm.g.As, A16,  m0, 128, k0)
        STAGE_TILE(sm.g.Bs, Wi16, o0, 128, k0)
        __syncthreads();   // drains vmcnt (DMA complete) before ds_reads
#pragma unroll
        for (int ks = 0; ks < 2; ++ks) {
            bfrag a[2], bi[2];
#pragma unroll
            for (int mt = 0; mt < 2; ++mt)
                a[mt] = *fragp(sm.g.As, wm * 32 + mt * 16 + lr, ks * 4 + quad);
#pragma unroll
            for (int nt = 0; nt < 2; ++nt)
                bi[nt] = *fragp(sm.g.Bs, wn * 32 + nt * 16 + lr, ks * 4 + quad);
#pragma unroll
            for (int mt = 0; mt < 2; ++mt)
#pragma unroll
                for (int nt = 0; nt < 2; ++nt)
                    ai[mt][nt] = __builtin_amdgcn_mfma_f32_16x16x32_bf16(a[mt], bi[nt], ai[mt][nt], 0, 0, 0);
        }
        __syncthreads();
    }
    // epilogue: xf16
#pragma unroll
    for (int mt = 0; mt < 2; ++mt)
#pragma unroll
        for (int nt = 0; nt < 2; ++nt)
#pragma unroll
            for (int r = 0; r < 4; ++r)
                sm.c.Cs[(wm * 32 + mt * 16 + quad * 4 + r) * 72 + wn * 32 + nt * 16 + lr] = f2b(ai[mt][nt][r]);
    __syncthreads();
#pragma unroll
    for (int it = 0; it < 2; ++it) {
        int e = it * 256 + tid;
        int row = e >> 3, c8 = (e & 7) * 8;
        *(uint4*)(xf16 + (long)(m0 + row) * C2 + o0 + c8) = *(const uint4*)&sm.c.Cs[row * 72 + c8];
    }
}

// ---------------------------------------------------------------------------
// GAT GEMM (K=256): h = xf@W^T + fused attention scores. Grid 1600, 256 thr.
// M-tile 64, BK=64 (4 k-steps). Staging via global_load_lds.
// ---------------------------------------------------------------------------
__global__ __launch_bounds__(256) void gat_gemm_kernel(
    const unsigned short* __restrict__ A16,
    const unsigned short* __restrict__ W16,
    unsigned short* __restrict__ Cout,
    const float* __restrict__ asrc, const float* __restrict__ adst,
    float* __restrict__ als_out, float* __restrict__ ald_out)
{
    __shared__ SmemNu sm;
    const int tid = threadIdx.x;
    int m0, o0; gemm_tile_ids(blockIdx.x, m0, o0);
    const int lane = tid & 63, wv = tid >> 6;
    const int wm = wv >> 1, wn = wv & 1;
    const int lr = lane & 15, quad = lane >> 4;

    ffrag acc[2][2];
#pragma unroll
    for (int mt = 0; mt < 2; ++mt)
#pragma unroll
        for (int nt = 0; nt < 2; ++nt) acc[mt][nt] = (ffrag){0,0,0,0};

    for (int k0 = 0; k0 < 256; k0 += 64) {
        STAGE_TILE(sm.g.As, A16, m0, C2, k0)
        STAGE_TILE(sm.g.Bs, W16, o0, C2, k0)
        __syncthreads();
#pragma unroll
        for (int ks = 0; ks < 2; ++ks) {
            bfrag a[2], b[2];
#pragma unroll
            for (int mt = 0; mt < 2; ++mt)
                a[mt] = *fragp(sm.g.As, wm * 32 + mt * 16 + lr, ks * 4 + quad);
#pragma unroll
            for (int nt = 0; nt < 2; ++nt)
                b[nt] = *fragp(sm.g.Bs, wn * 32 + nt * 16 + lr, ks * 4 + quad);
#pragma unroll
            for (int mt = 0; mt < 2; ++mt)
#pragma unroll
                for (int nt = 0; nt < 2; ++nt)
                    acc[mt][nt] = __builtin_amdgcn_mfma_f32_16x16x32_bf16(a[mt], b[nt], acc[mt][nt], 0, 0, 0);
        }
        __syncthreads();
    }
    // attention epilogue: wave covers head = (o0/32)+wn, d = nt*16+lr
    {
        const int head = (o0 >> 5) + wn;
        const float as0 = asrc[head * 32 + lr], as1 = asrc[head * 32 + 16 + lr];
        const float ad0 = adst[head * 32 + lr], ad1 = adst[head * 32 + 16 + lr];
#pragma unroll
        for (int mt = 0; mt < 2; ++mt)
#pragma unroll
            for (int r = 0; r < 4; ++r) {
                float ps = acc[mt][0][r] * as0 + acc[mt][1][r] * as1;
                float pd = acc[mt][0][r] * ad0 + acc[mt][1][r] * ad1;
#pragma unroll
                for (int sh = 1; sh < 16; sh <<= 1) {
                    ps += __shfl_xor(ps, sh);
                    pd += __shfl_xor(pd, sh);
                }
                if (lr == 0) {
                    int m = m0 + wm * 32 + mt * 16 + quad * 4 + r;
                    als_out[m * 8 + head] = ps;
                    ald_out[m * 8 + head] = pd;
                }
            }
    }
    // C store via LDS
#pragma unroll
    for (int mt = 0; mt < 2; ++mt)
#pragma unroll
        for (int nt = 0; nt < 2; ++nt)
#pragma unroll
            for (int r = 0; r < 4; ++r)
                sm.c.Cs[(wm * 32 + mt * 16 + quad * 4 + r) * 72 + wn * 32 + nt * 16 + lr] = f2b(acc[mt][nt][r]);
    __syncthreads();
#pragma unroll
    for (int it = 0; it < 2; ++it) {
        int e = it * 256 + tid;
        int row = e >> 3, c8 = (e & 7) * 8;
        *(uint4*)(Cout + (long)(m0 + row) * C2 + o0 + c8) = *(const uint4*)&sm.c.Cs[row * 72 + c8];
    }
}

// ---------------------------------------------------------------------------
// Aggregation: 8 nodes/block, 32 thr/node, 8 bf16 channels/thread. Grid 3200.
// BARRIER-FREE main path: each thread computes its own (node, head) softmax
// in registers (11 scalar al_s loads, wave-broadcast across the 4 threads
// sharing a head) — no es/alpha LDS phases, no barriers.
// If means != nullptr (last hop): block-reduce colsum -> atomicAdd into one
// of MSLOTS slots (spread: ~50 serialized RMWs/address instead of 3200).
// ---------------------------------------------------------------------------
__global__ __launch_bounds__(256) void aggregate_kernel(
    const unsigned short* __restrict__ h16,
    const float* __restrict__ al_s,
    const float* __restrict__ al_d,
    const float* __restrict__ bnA,
    const float* __restrict__ bnB,
    unsigned short* __restrict__ xf16,
    float* __restrict__ means)
{
    const int SI[11] = { 1, 1, 1, 0, 0, -1, -1, -1, -2,  0, 0};
    const int SJ[11] = { 1, 0,-1, 1,-1,  1,  0, -1,  0, -2, 0};
    __shared__ float part[4][256];

    const int t = threadIdx.x;
    const int ln = t >> 5;
    const int l = t & 31;
    const int n = blockIdx.x * 8 + ln;
    const int i = n / WW, j = n % WW;
    const int c8 = l * 8;
    const int hd = l >> 2;

    // neighbor indices + validity
    int srcn[11]; bool okm[11];
#pragma unroll
    for (int k = 0; k < 11; ++k) {
        int si = i + SI[k], sj = j + SJ[k];
        bool ok = (si >= 0) & (si < HH) & (sj >= 0) & (sj < WW);
        okm[k] = ok;
        srcn[k] = ok ? si * WW + sj : n;
    }

    // per-thread softmax over incoming edges for head hd (4x redundant within
    // wave -> loads broadcast; no LDS, no barriers)
    float e[11];
    {
        const float ald = al_d[n * 8 + hd];
        float mx = -1e30f;
#pragma unroll
        for (int k = 0; k < 11; ++k) {
            float s = al_s[(long)srcn[k] * 8 + hd];
            float v = s + ald;
            v = v > 0.f ? v : 0.2f * v;
            v = okm[k] ? v : -1e30f;
            e[k] = v;
            mx = fmaxf(mx, v);
        }
        float denom = 0.f;
#pragma unroll
        for (int k = 0; k < 11; ++k) {
            float p = __expf(e[k] - mx);
            e[k] = p;
            denom += p;
        }
        const float inv = 1.f / (denom + 1e-16f);
#pragma unroll
        for (int k = 0; k < 11; ++k) e[k] *= inv;   // alpha
    }

    // batched gather: all 12 uint4 loads issued before any consumption
    uint4 hv[11];
#pragma unroll
    for (int k = 0; k < 11; ++k)
        hv[k] = *(const uint4*)(h16 + (long)srcn[k] * C2 + c8);
    uint4 rv = *(const uint4*)(xf16 + (long)n * C2 + c8);

    float a0=0.f,a1=0.f,a2=0.f,a3=0.f,a4=0.f,a5=0.f,a6=0.f,a7=0.f;
#pragma unroll
    for (int k = 0; k < 11; ++k) {
        float al = e[k];
        a0 += al * lo16f(hv[k].x); a1 += al * hi16f(hv[k].x);
        a2 += al * lo16f(hv[k].y); a3 += al * hi16f(hv[k].y);
        a4 += al * lo16f(hv[k].z); a5 += al * hi16f(hv[k].z);
        a6 += al * lo16f(hv[k].w); a7 += al * hi16f(hv[k].w);
    }
    float acc8[8] = {a0,a1,a2,a3,a4,a5,a6,a7};
    float res[8] = {lo16f(rv.x),hi16f(rv.x),lo16f(rv.y),hi16f(rv.y),
                    lo16f(rv.z),hi16f(rv.z),lo16f(rv.w),hi16f(rv.w)};
    float out[8];
#pragma unroll
    for (int q = 0; q < 8; ++q) {
        int c = c8 + q;
        float g = acc8[q] * bnA[c] + bnB[c];
        out[q] = fmaxf(g, 0.f) + res[q];
    }
    ushort4 o16a, o16b;
    o16a.x = f2b(out[0]); o16a.y = f2b(out[1]); o16a.z = f2b(out[2]); o16a.w = f2b(out[3]);
    o16b.x = f2b(out[4]); o16b.y = f2b(out[5]); o16b.z = f2b(out[6]); o16b.w = f2b(out[7]);
    *(ushort4*)(xf16 + (long)n * C2 + c8)     = o16a;
    *(ushort4*)(xf16 + (long)n * C2 + c8 + 4) = o16b;

    // fused colsum for SE (last hop only), atomic-spread over MSLOTS slots
    if (means) {
        float s8[8];
#pragma unroll
        for (int q = 0; q < 8; ++q) {
            s8[q] = out[q];
            s8[q] += __shfl_xor(s8[q], 32);    // combine node pair within wave
        }
        const int wvi = t >> 6;
        if ((t & 63) < 32) {
#pragma unroll
            for (int q = 0; q < 8; ++q) part[wvi][c8 + q] = s8[q];
        }
        __syncthreads();
        {
            float v = part[0][t] + part[1][t] + part[2][t] + part[3][t];
            atomicAdd(&means[(blockIdx.x & (MSLOTS - 1)) * 256 + t], v);
        }
    }
}

// ---------------------------------------------------------------------------
// SE vector, computed ONCE: cs = slot-sum(means); mv = cs@Wout^T / N;
// hv = relu(W1@mv + b1); sv = sigmoid(W2@hv + b2). Grid 1 x 256 thr.
// ---------------------------------------------------------------------------
__global__ __launch_bounds__(256) void se_kernel(
    const unsigned short* __restrict__ W16,     // Wout bf16 [256][256]
    const float* __restrict__ means,
    const float* __restrict__ cvt,
    float* __restrict__ sv_out)
{
    __shared__ float cs[256], mv[256], hv[64];
    const int t = threadIdx.x;
    {
        float s0=0,s1=0,s2=0,s3=0,s4=0,s5=0,s6=0,s7=0;
#pragma unroll 2
        for (int sl = 0; sl < MSLOTS; sl += 8) {
            s0 += means[(sl+0)*256 + t]; s1 += means[(sl+1)*256 + t];
            s2 += means[(sl+2)*256 + t]; s3 += means[(sl+3)*256 + t];
            s4 += means[(sl+4)*256 + t]; s5 += means[(sl+5)*256 + t];
            s6 += means[(sl+6)*256 + t]; s7 += means[(sl+7)*256 + t];
        }
        cs[t] = ((s0+s1)+(s2+s3)) + ((s4+s5)+(s6+s7));
    }
    __syncthreads();
    {
        float s = 0.f;
        const unsigned short* wr = W16 + (long)t * C2;
#pragma unroll 4
        for (int k = 0; k < 256; k += 8) {
            uint4 w = *(const uint4*)(wr + k);
            s += cs[k]   * lo16f(w.x) + cs[k+1] * hi16f(w.x)
               + cs[k+2] * lo16f(w.y) + cs[k+3] * hi16f(w.y)
               + cs[k+4] * lo16f(w.z) + cs[k+5] * hi16f(w.z)
               + cs[k+6] * lo16f(w.w) + cs[k+7] * hi16f(w.w);
        }
        mv[t] = s * (1.0f / 25600.0f);
    }
    __syncthreads();
    if (t < 64) {
        const float* w1 = cvt + C_SEW1 + t * 256;
        float s = cvt[C_SEB1 + t];
        for (int cc = 0; cc < 256; cc += 4) {
            float4 w = *(const float4*)(w1 + cc);
            s += w.x * mv[cc] + w.y * mv[cc+1] + w.z * mv[cc+2] + w.w * mv[cc+3];
        }
        hv[t] = fmaxf(s, 0.f);
    }
    __syncthreads();
    {
        const float* w2 = cvt + C_SEW2 + t * 64;
        float s = cvt[C_SEB2 + t];
        for (int k = 0; k < 64; k += 4) {
            float4 w = *(const float4*)(w2 + k);
            s += w.x * hv[k] + w.y * hv[k+1] + w.z * hv[k+2] + w.w * hv[k+3];
        }
        sv_out[t] = 1.0f / (1.0f + __expf(-s));
    }
}

// ---------------------------------------------------------------------------
// Final: y-tile = xf@Wout^T (K=256) AND id-tile = xT@Wid^T (K=128, recomputed
// here instead of a stored idb round-trip), out[c][n] = y*sv + id,
// transposed store. Grid 1600, 256 thr. Staging via global_load_lds.
// ---------------------------------------------------------------------------
__global__ __launch_bounds__(256) void final_gemm_kernel(
    const unsigned short* __restrict__ x_probe,
    const unsigned short* __restrict__ A16,       // xf post-hop2 [NN][256]
    const unsigned short* __restrict__ W16,       // Wout bf16 [256][256]
    const unsigned short* __restrict__ AT16,      // xT bf16 [NN][128]
    const unsigned short* __restrict__ Wd16,      // Wid bf16 [256][128]
    const float* __restrict__ sv,
    void* __restrict__ outp)
{
    __shared__ SmemFu sm;
    const bool f32o = probe_f32(x_probe);
    const int tid = threadIdx.x;
    int m0, o0; gemm_tile_ids(blockIdx.x, m0, o0);
    const int lane = tid & 63, wv = tid >> 6;
    const int wm = wv >> 1, wn = wv & 1;
    const int lr = lane & 15, quad = lane >> 4;

    ffrag acc[2][2], accI[2][2];
#pragma unroll
    for (int mt = 0; mt < 2; ++mt)
#pragma unroll
        for (int nt = 0; nt < 2; ++nt) { acc[mt][nt] = (ffrag){0,0,0,0}; accI[mt][nt] = (ffrag){0,0,0,0}; }

    // y = xf @ Wout^T (K=256)
    for (int k0 = 0; k0 < 256; k0 += 64) {
        STAGE_TILE(sm.g.As, A16, m0, C2, k0)
        STAGE_TILE(sm.g.Bs, W16, o0, C2, k0)
        __syncthreads();
#pragma unroll
        for (int ks = 0; ks < 2; ++ks) {
            bfrag a[2], b[2];
#pragma unroll
            for (int mt = 0; mt < 2; ++mt)
                a[mt] = *fragp(sm.g.As, wm * 32 + mt * 16 + lr, ks * 4 + quad);
#pragma unroll
            for (int nt = 0; nt < 2; ++nt)
                b[nt] = *fragp(sm.g.Bs, wn * 32 + nt * 16 + lr, ks * 4 + quad);
#pragma unroll
            for (int mt = 0; mt < 2; ++mt)
#pragma unroll
                for (int nt = 0; nt < 2; ++nt)
                    acc[mt][nt] = __builtin_amdgcn_mfma_f32_16x16x32_bf16(a[mt], b[nt], acc[mt][nt], 0, 0, 0);
        }
        __syncthreads();
    }
    // id = xT @ Wid^T (K=128)
    for (int k0 = 0; k0 < 128; k0 += 64) {
        STAGE_TILE(sm.g.As, AT16, m0, 128, k0)
        STAGE_TILE(sm.g.Bs, Wd16, o0, 128, k0)
        __syncthreads();
#pragma unroll
        for (int ks = 0; ks < 2; ++ks) {
            bfrag a[2], b[2];
#pragma unroll
            for (int mt = 0; mt < 2; ++mt)
                a[mt] = *fragp(sm.g.As, wm * 32 + mt * 16 + lr, ks * 4 + quad);
#pragma unroll
            for (int nt = 0; nt < 2; ++nt)
                b[nt] = *fragp(sm.g.Bs, wn * 32 + nt * 16 + lr, ks * 4 + quad);
#pragma unroll
            for (int mt = 0; mt < 2; ++mt)
#pragma unroll
                for (int nt = 0; nt < 2; ++nt)
                    accI[mt][nt] = __builtin_amdgcn_mfma_f32_16x16x32_bf16(a[mt], b[nt], accI[mt][nt], 0, 0, 0);
        }
        __syncthreads();
    }

    // deposit y*sv + id into T[col][row] (fp32), then coalesced transposed store
#pragma unroll
    for (int mt = 0; mt < 2; ++mt)
#pragma unroll
        for (int nt = 0; nt < 2; ++nt) {
            int cl = wn * 32 + nt * 16 + lr;          // local col 0..63
            float s = sv[o0 + cl];
#pragma unroll
            for (int r = 0; r < 4; ++r) {
                int row = wm * 32 + mt * 16 + quad * 4 + r;
                float v = acc[mt][nt][r] * s + accI[mt][nt][r];
                sm.t.T[cl * 73 + row] = v;
            }
        }
    __syncthreads();
#pragma unroll
    for (int it = 0; it < 16; ++it) {
        int e = it * 256 + tid;
        int cc = e >> 6, nn = e & 63;
        long idx = (long)(o0 + cc) * NN + m0 + nn;
        float v = sm.t.T[cc * 73 + nn];
        if (f32o) ((float*)outp)[idx] = v;
        else      ((unsigned short*)outp)[idx] = f2b(v);
    }
}

extern "C" void kernel_launch(void* const* d_in, const int* in_sizes, int n_in,
                              void* d_out, int out_size, void* d_ws, size_t ws_size,
                              hipStream_t stream) {
    float* ws = (float*)d_ws;
    float* cvt   = ws;                          // C_END small fp32 params
    float* means = ws + 35200;                  // MSLOTS x 256
    float* svb   = means + MSLOTS * 256;        // 256
    float* als   = svb + 256;                   // 204800
    float* ald   = als + 204800;
    unsigned short* wb16  = (unsigned short*)(ald + 204800);  // 262144
    unsigned short* xT16  = wb16 + B_WEND;                    // 25600*128
    unsigned short* xf16  = xT16 + NN * 128;                  // 25600*256
    unsigned short* h16   = xf16 + NN * 256;                  // 25600*256

    const unsigned short* xp = (const unsigned short*)d_in[0];

    dim3 b256(256);

    prep_kernel<<<400, b256, 0, stream>>>(
        xp, d_in[2], d_in[1], d_in[3], d_in[11],
        d_in[4], d_in[5], d_in[6], d_in[7], d_in[8], d_in[9], d_in[10],
        d_in[12], d_in[13], d_in[14], d_in[15],
        wb16, cvt, means, xT16);

    mfma_gemm_kernel<<<1600, b256, 0, stream>>>(
        xT16, wb16 + B_WIN, xf16);

    for (int l = 0; l < 2; ++l) {
        gat_gemm_kernel<<<1600, b256, 0, stream>>>(
            xf16, wb16 + B_WGAT + l * 65536, h16,
            cvt + C_ASRC + l * 256, cvt + C_ADST + l * 256, als, ald);
        aggregate_kernel<<<NN / 8, b256, 0, stream>>>(h16, als, ald,
            cvt + C_BNA + l * 256, cvt + C_BNB + l * 256, xf16,
            (l == 1) ? means : nullptr);
    }

    se_kernel<<<1, b256, 0, stream>>>(wb16 + B_WOUT, means, cvt, svb);

    final_gemm_kernel<<<1600, b256, 0, stream>>>(
        xp, xf16, wb16 + B_WOUT, xT16, wb16 + B_WID, svb, d_out);
}

// Round 16
// 197.421 us; speedup vs baseline: 1.1042x; 1.0227x over previous
//
#include <hip/hip_runtime.h>

#define NN 25600      // nodes = 160*160
#define HH 160
#define WW 160
#define C2 256
#define MSLOTS 64     // colsum atomic spreading slots

// ---- bf16 weight pack offsets (ushorts) ----
#define B_WIN   0
#define B_WID   32768
#define B_WGAT  65536      // 2 layers x 65536
#define B_WOUT  196608
#define B_WEND  262144

// ---- small fp32 param offsets inside cvt (floats) ----
#define C_BNA   0          // 2x256 BN scale
#define C_BNB   512        // 2x256 BN shift (bias/mean folded)
#define C_ASRC  1024       // 2x256
#define C_ADST  1536       // 2x256
#define C_SEW1  2048       // 64x256
#define C_SEB1  18432      // 64
#define C_SEW2  18496      // 256x64
#define C_SEB2  34880      // 256
#define C_END   35136

typedef __attribute__((ext_vector_type(8))) short bfrag;   // 8 bf16 (4 VGPRs)
typedef __attribute__((ext_vector_type(4))) float ffrag;   // 4 fp32 acc

__device__ __forceinline__ float b2f(unsigned short u) {
    union { unsigned int ui; float f; } v; v.ui = ((unsigned int)u) << 16; return v.f;
}
__device__ __forceinline__ unsigned short f2b(float f) {
    union { float f; unsigned int u; } v; v.f = f;
    unsigned int u = v.u;
    unsigned int r = (u + 0x7FFFu + ((u >> 16) & 1u)) >> 16;
    return (unsigned short)r;
}
__device__ __forceinline__ float lo16f(unsigned int w) {
    union { unsigned int ui; float f; } v; v.ui = w << 16; return v.f;
}
__device__ __forceinline__ float hi16f(unsigned int w) {
    union { unsigned int ui; float f; } v; v.ui = w & 0xFFFF0000u; return v.f;
}
// Wave-uniform dtype probe on first 512 halfwords of x.
__device__ __forceinline__ bool probe_f32(const unsigned short* __restrict__ x) {
    int l = threadIdx.x & 63;
    bool wild = false;
#pragma unroll
    for (int i = 0; i < 8; ++i) {
        float v = b2f(x[l * 8 + i]);
        wild |= !(fabsf(v) < 1e6f);
    }
    return __any(wild);
}
__device__ __forceinline__ float ldf(const void* p, long i, bool f32) {
    return f32 ? ((const float*)p)[i] : b2f(((const unsigned short*)p)[i]);
}

// XCD-grouping swizzle for the 1600-block GEMM grids (1600 = 8 XCDs x 200):
// neutral at this size (round 13) but free; helps if problem scales past L3.
__device__ __forceinline__ void gemm_tile_ids(int bid, int& m0, int& o0) {
    int w = (bid & 7) * 200 + (bid >> 3);
    m0 = (w >> 2) * 64;
    o0 = (w & 3) * 64;
}

// Swizzled fragment pointer into an unpadded [64][64]-ushort LDS tile:
// chunk (16B) index is XOR'd with (row&7); matches the pre-swizzled
// global source used by the global_load_lds staging (rule: both sides).
__device__ __forceinline__ const bfrag* fragp(const unsigned short* buf, int row, int c8) {
    return (const bfrag*)(buf + row * 64 + ((c8 ^ (row & 7)) << 3));
}

// ---------------------------------------------------------------------------
// prep: pack weights bf16, fold BN, convert small params, zero means slots,
// AND transpose x -> bf16 [25600][128]. Grid = 1600 (16 nodes/block in the
// transpose; was 400x64 -> only 1.56 waves/SIMD, latency-starved).
// ---------------------------------------------------------------------------
__global__ __launch_bounds__(256) void prep_kernel(
    const unsigned short* __restrict__ xp,
    const void* pwin, const void* pwid, const void* pwgat, const void* pwout,
    const void* pasrc, const void* padst, const void* pgbias,
    const void* pbng, const void* pbnb, const void* pbnm, const void* pbnv,
    const void* psew1, const void* pseb1, const void* psew2, const void* pseb2,
    unsigned short* __restrict__ wb, float* __restrict__ cvt,
    float* __restrict__ means, unsigned short* __restrict__ xT)
{
    __shared__ unsigned short T[16 * 136];
    const bool f32 = probe_f32(xp);
    const int tid = threadIdx.x;
    const int bid = blockIdx.x;
    const int gid = bid * 256 + tid;
    const int stride = gridDim.x * 256;

    for (int i = gid; i < MSLOTS * 256; i += stride) means[i] = 0.f;

    for (int i = gid; i < B_WEND; i += stride) {
        const void* s; int o;
        if      (i < B_WID)   { s = pwin;  o = i - B_WIN; }
        else if (i < B_WGAT)  { s = pwid;  o = i - B_WID; }
        else if (i < B_WOUT)  { s = pwgat; o = i - B_WGAT; }
        else                  { s = pwout; o = i - B_WOUT; }
        wb[i] = f32 ? f2b(((const float*)s)[o]) : ((const unsigned short*)s)[o];
    }
    for (int i = gid; i < 512; i += stride) {
        float sc = ldf(pbng, i, f32) * rsqrtf(ldf(pbnv, i, f32) + 1e-5f);
        cvt[C_BNA + i] = sc;
        cvt[C_BNB + i] = (ldf(pgbias, i, f32) - ldf(pbnm, i, f32)) * sc + ldf(pbnb, i, f32);
        cvt[C_ASRC + i] = ldf(pasrc, i, f32);
        cvt[C_ADST + i] = ldf(padst, i, f32);
    }
    for (int i = gid; i < 16384; i += stride) {
        cvt[C_SEW1 + i] = ldf(psew1, i, f32);
        cvt[C_SEW2 + i] = ldf(psew2, i, f32);
    }
    for (int i = gid; i < 64; i += stride)  cvt[C_SEB1 + i] = ldf(pseb1, i, f32);
    for (int i = gid; i < 256; i += stride) cvt[C_SEB2 + i] = ldf(pseb2, i, f32);

    // transpose slice: 16 nodes per block (grid 1600 covers 25600)
    {
        const int n0 = bid * 16;
        const int nl = tid & 15;           // node within block
        const int cb = tid >> 4;           // channel base lane group (0..15)
#pragma unroll
        for (int i = 0; i < 8; ++i) {
            int c = i * 16 + cb;
            long idx = (long)c * NN + n0 + nl;
            T[nl * 136 + c] = f32 ? f2b(((const float*)xp)[idx]) : xp[idx];
        }
        __syncthreads();
        {
            int n = tid >> 4, c0 = (tid & 15) * 8;   // 256 uint4 = 16 nodes x 128 c
            uint4 v = *(const uint4*)&T[n * 136 + c0];
            *(uint4*)(xT + (long)(n0 + n) * 128 + c0) = v;
        }
    }
}

// ---------------------------------------------------------------------------
// LDS layouts. GEMM staging tiles are UNPADDED [64][64] ushort (8 KB each):
// global_load_lds requires lane-linear destinations; bank conflicts on the
// fragment reads are broken by the XOR chunk swizzle (fragp / staging).
// C-staging keeps the padded 72-ushort rows (plain stores).
// ---------------------------------------------------------------------------
struct SmemC64 { unsigned short Cs[64 * 72]; };                      //  9216 B
struct SmemGu  { unsigned short As[4096], Bs[4096]; };               // 16384 B
union  SmemNu  { SmemGu g; SmemC64 c; };
struct SmemT   { float T[64 * 73]; };                                // 18688 B
union  SmemFu  { SmemGu g; SmemT t; };

// Stage one 64x64-ushort tile (64 rows x 64 cols of bf16) from global
// (row stride LDA ushorts, col offset k0) into LDS via global_load_lds,
// with pre-swizzled per-lane global chunk (q ^= row&7), linear LDS dest.
#define STAGE_TILE(DST, SRC, ROW0, LDA, K0)                                       \
    {                                                                             \
        _Pragma("unroll")                                                         \
        for (int ii = 0; ii < 2; ++ii) {                                          \
            int e = tid + ii * 256;                                               \
            int row = e >> 3;                                                     \
            int q = (e & 7) ^ (row & 7);                                          \
            __builtin_amdgcn_global_load_lds(                                     \
                (const unsigned int*)((SRC) + (long)((ROW0) + row) * (LDA) + (K0) + q * 8), \
                (unsigned int*)&(DST)[e * 8], 16, 0, 0);                          \
        }                                                                         \
    }

// ---------------------------------------------------------------------------
// MFMA GEMM (K=128): xf16 = xT@Win^T. Grid 1600, 256 thr.
// M-tile 64, BK=64 (2 k-steps). (idb is recomputed in final_gemm.)
// ---------------------------------------------------------------------------
__global__ __launch_bounds__(256) void mfma_gemm_kernel(
    const unsigned short* __restrict__ A16,
    const unsigned short* __restrict__ Wi16,
    unsigned short* __restrict__ xf16)
{
    __shared__ SmemNu sm;
    const int tid = threadIdx.x;
    int m0, o0; gemm_tile_ids(blockIdx.x, m0, o0);
    const int lane = tid & 63, wv = tid >> 6;
    const int wm = wv >> 1, wn = wv & 1;
    const int lr = lane & 15, quad = lane >> 4;

    ffrag ai[2][2];
#pragma unroll
    for (int mt = 0; mt < 2; ++mt)
#pragma unroll
        for (int nt = 0; nt < 2; ++nt) ai[mt][nt] = (ffrag){0,0,0,0};

    for (int k0 = 0; k0 < 128; k0 += 64) {
        STAGE_TILE(sm.g.As, A16,  m0, 128, k0)
        STAGE_TILE(sm.g.Bs, Wi16, o0, 128, k0)
        __syncthreads();   // drains vmcnt (DMA complete) before ds_reads
#pragma unroll
        for (int ks = 0; ks < 2; ++ks) {
            bfrag a[2], bi[2];
#pragma unroll
            for (int mt = 0; mt < 2; ++mt)
                a[mt] = *fragp(sm.g.As, wm * 32 + mt * 16 + lr, ks * 4 + quad);
#pragma unroll
            for (int nt = 0; nt < 2; ++nt)
                bi[nt] = *fragp(sm.g.Bs, wn * 32 + nt * 16 + lr, ks * 4 + quad);
#pragma unroll
            for (int mt = 0; mt < 2; ++mt)
#pragma unroll
                for (int nt = 0; nt < 2; ++nt)
                    ai[mt][nt] = __builtin_amdgcn_mfma_f32_16x16x32_bf16(a[mt], bi[nt], ai[mt][nt], 0, 0, 0);
        }
        __syncthreads();
    }
    // epilogue: xf16
#pragma unroll
    for (int mt = 0; mt < 2; ++mt)
#pragma unroll
        for (int nt = 0; nt < 2; ++nt)
#pragma unroll
            for (int r = 0; r < 4; ++r)
                sm.c.Cs[(wm * 32 + mt * 16 + quad * 4 + r) * 72 + wn * 32 + nt * 16 + lr] = f2b(ai[mt][nt][r]);
    __syncthreads();
#pragma unroll
    for (int it = 0; it < 2; ++it) {
        int e = it * 256 + tid;
        int row = e >> 3, c8 = (e & 7) * 8;
        *(uint4*)(xf16 + (long)(m0 + row) * C2 + o0 + c8) = *(const uint4*)&sm.c.Cs[row * 72 + c8];
    }
}

// ---------------------------------------------------------------------------
// GAT GEMM (K=256): h = xf@W^T + fused attention scores. Grid 1600, 256 thr.
// M-tile 64, BK=64 (4 k-steps). Staging via global_load_lds.
// ---------------------------------------------------------------------------
__global__ __launch_bounds__(256) void gat_gemm_kernel(
    const unsigned short* __restrict__ A16,
    const unsigned short* __restrict__ W16,
    unsigned short* __restrict__ Cout,
    const float* __restrict__ asrc, const float* __restrict__ adst,
    float* __restrict__ als_out, float* __restrict__ ald_out)
{
    __shared__ SmemNu sm;
    const int tid = threadIdx.x;
    int m0, o0; gemm_tile_ids(blockIdx.x, m0, o0);
    const int lane = tid & 63, wv = tid >> 6;
    const int wm = wv >> 1, wn = wv & 1;
    const int lr = lane & 15, quad = lane >> 4;

    ffrag acc[2][2];
#pragma unroll
    for (int mt = 0; mt < 2; ++mt)
#pragma unroll
        for (int nt = 0; nt < 2; ++nt) acc[mt][nt] = (ffrag){0,0,0,0};

    for (int k0 = 0; k0 < 256; k0 += 64) {
        STAGE_TILE(sm.g.As, A16, m0, C2, k0)
        STAGE_TILE(sm.g.Bs, W16, o0, C2, k0)
        __syncthreads();
#pragma unroll
        for (int ks = 0; ks < 2; ++ks) {
            bfrag a[2], b[2];
#pragma unroll
            for (int mt = 0; mt < 2; ++mt)
                a[mt] = *fragp(sm.g.As, wm * 32 + mt * 16 + lr, ks * 4 + quad);
#pragma unroll
            for (int nt = 0; nt < 2; ++nt)
                b[nt] = *fragp(sm.g.Bs, wn * 32 + nt * 16 + lr, ks * 4 + quad);
#pragma unroll
            for (int mt = 0; mt < 2; ++mt)
#pragma unroll
                for (int nt = 0; nt < 2; ++nt)
                    acc[mt][nt] = __builtin_amdgcn_mfma_f32_16x16x32_bf16(a[mt], b[nt], acc[mt][nt], 0, 0, 0);
        }
        __syncthreads();
    }
    // attention epilogue: wave covers head = (o0/32)+wn, d = nt*16+lr
    {
        const int head = (o0 >> 5) + wn;
        const float as0 = asrc[head * 32 + lr], as1 = asrc[head * 32 + 16 + lr];
        const float ad0 = adst[head * 32 + lr], ad1 = adst[head * 32 + 16 + lr];
#pragma unroll
        for (int mt = 0; mt < 2; ++mt)
#pragma unroll
            for (int r = 0; r < 4; ++r) {
                float ps = acc[mt][0][r] * as0 + acc[mt][1][r] * as1;
                float pd = acc[mt][0][r] * ad0 + acc[mt][1][r] * ad1;
#pragma unroll
                for (int sh = 1; sh < 16; sh <<= 1) {
                    ps += __shfl_xor(ps, sh);
                    pd += __shfl_xor(pd, sh);
                }
                if (lr == 0) {
                    int m = m0 + wm * 32 + mt * 16 + quad * 4 + r;
                    als_out[m * 8 + head] = ps;
                    ald_out[m * 8 + head] = pd;
                }
            }
    }
    // C store via LDS
#pragma unroll
    for (int mt = 0; mt < 2; ++mt)
#pragma unroll
        for (int nt = 0; nt < 2; ++nt)
#pragma unroll
            for (int r = 0; r < 4; ++r)
                sm.c.Cs[(wm * 32 + mt * 16 + quad * 4 + r) * 72 + wn * 32 + nt * 16 + lr] = f2b(acc[mt][nt][r]);
    __syncthreads();
#pragma unroll
    for (int it = 0; it < 2; ++it) {
        int e = it * 256 + tid;
        int row = e >> 3, c8 = (e & 7) * 8;
        *(uint4*)(Cout + (long)(m0 + row) * C2 + o0 + c8) = *(const uint4*)&sm.c.Cs[row * 72 + c8];
    }
}

// ---------------------------------------------------------------------------
// Aggregation: 8 nodes/block, 32 thr/node, 8 bf16 channels/thread. Grid 3200.
// BARRIER-FREE main path: each thread computes its own (node, head) softmax
// in registers (11 scalar al_s loads, wave-broadcast across the 4 threads
// sharing a head) — no es/alpha LDS phases, no barriers.
// If means != nullptr (last hop): block-reduce colsum -> atomicAdd into one
// of MSLOTS slots (spread: ~50 serialized RMWs/address instead of 3200).
// ---------------------------------------------------------------------------
__global__ __launch_bounds__(256) void aggregate_kernel(
    const unsigned short* __restrict__ h16,
    const float* __restrict__ al_s,
    const float* __restrict__ al_d,
    const float* __restrict__ bnA,
    const float* __restrict__ bnB,
    unsigned short* __restrict__ xf16,
    float* __restrict__ means)
{
    const int SI[11] = { 1, 1, 1, 0, 0, -1, -1, -1, -2,  0, 0};
    const int SJ[11] = { 1, 0,-1, 1,-1,  1,  0, -1,  0, -2, 0};
    __shared__ float part[4][256];

    const int t = threadIdx.x;
    const int ln = t >> 5;
    const int l = t & 31;
    const int n = blockIdx.x * 8 + ln;
    const int i = n / WW, j = n % WW;
    const int c8 = l * 8;
    const int hd = l >> 2;

    // neighbor indices + validity
    int srcn[11]; bool okm[11];
#pragma unroll
    for (int k = 0; k < 11; ++k) {
        int si = i + SI[k], sj = j + SJ[k];
        bool ok = (si >= 0) & (si < HH) & (sj >= 0) & (sj < WW);
        okm[k] = ok;
        srcn[k] = ok ? si * WW + sj : n;
    }

    // per-thread softmax over incoming edges for head hd (4x redundant within
    // wave -> loads broadcast; no LDS, no barriers)
    float e[11];
    {
        const float ald = al_d[n * 8 + hd];
        float mx = -1e30f;
#pragma unroll
        for (int k = 0; k < 11; ++k) {
            float s = al_s[(long)srcn[k] * 8 + hd];
            float v = s + ald;
            v = v > 0.f ? v : 0.2f * v;
            v = okm[k] ? v : -1e30f;
            e[k] = v;
            mx = fmaxf(mx, v);
        }
        float denom = 0.f;
#pragma unroll
        for (int k = 0; k < 11; ++k) {
            float p = __expf(e[k] - mx);
            e[k] = p;
            denom += p;
        }
        const float inv = 1.f / (denom + 1e-16f);
#pragma unroll
        for (int k = 0; k < 11; ++k) e[k] *= inv;   // alpha
    }

    // batched gather: all 12 uint4 loads issued before any consumption
    uint4 hv[11];
#pragma unroll
    for (int k = 0; k < 11; ++k)
        hv[k] = *(const uint4*)(h16 + (long)srcn[k] * C2 + c8);
    uint4 rv = *(const uint4*)(xf16 + (long)n * C2 + c8);

    float a0=0.f,a1=0.f,a2=0.f,a3=0.f,a4=0.f,a5=0.f,a6=0.f,a7=0.f;
#pragma unroll
    for (int k = 0; k < 11; ++k) {
        float al = e[k];
        a0 += al * lo16f(hv[k].x); a1 += al * hi16f(hv[k].x);
        a2 += al * lo16f(hv[k].y); a3 += al * hi16f(hv[k].y);
        a4 += al * lo16f(hv[k].z); a5 += al * hi16f(hv[k].z);
        a6 += al * lo16f(hv[k].w); a7 += al * hi16f(hv[k].w);
    }
    float acc8[8] = {a0,a1,a2,a3,a4,a5,a6,a7};
    float res[8] = {lo16f(rv.x),hi16f(rv.x),lo16f(rv.y),hi16f(rv.y),
                    lo16f(rv.z),hi16f(rv.z),lo16f(rv.w),hi16f(rv.w)};
    float out[8];
#pragma unroll
    for (int q = 0; q < 8; ++q) {
        int c = c8 + q;
        float g = acc8[q] * bnA[c] + bnB[c];
        out[q] = fmaxf(g, 0.f) + res[q];
    }
    ushort4 o16a, o16b;
    o16a.x = f2b(out[0]); o16a.y = f2b(out[1]); o16a.z = f2b(out[2]); o16a.w = f2b(out[3]);
    o16b.x = f2b(out[4]); o16b.y = f2b(out[5]); o16b.z = f2b(out[6]); o16b.w = f2b(out[7]);
    *(ushort4*)(xf16 + (long)n * C2 + c8)     = o16a;
    *(ushort4*)(xf16 + (long)n * C2 + c8 + 4) = o16b;

    // fused colsum for SE (last hop only), atomic-spread over MSLOTS slots
    if (means) {
        float s8[8];
#pragma unroll
        for (int q = 0; q < 8; ++q) {
            s8[q] = out[q];
            s8[q] += __shfl_xor(s8[q], 32);    // combine node pair within wave
        }
        const int wvi = t >> 6;
        if ((t & 63) < 32) {
#pragma unroll
            for (int q = 0; q < 8; ++q) part[wvi][c8 + q] = s8[q];
        }
        __syncthreads();
        {
            float v = part[0][t] + part[1][t] + part[2][t] + part[3][t];
            atomicAdd(&means[(blockIdx.x & (MSLOTS - 1)) * 256 + t], v);
        }
    }
}

// ---------------------------------------------------------------------------
// SE vector, computed ONCE: cs = slot-sum(means); mv = cs@Wout^T / N;
// hv = relu(W1@mv + b1); sv = sigmoid(W2@hv + b2). Grid 1 x 256 thr.
// ---------------------------------------------------------------------------
__global__ __launch_bounds__(256) void se_kernel(
    const unsigned short* __restrict__ W16,     // Wout bf16 [256][256]
    const float* __restrict__ means,
    const float* __restrict__ cvt,
    float* __restrict__ sv_out)
{
    __shared__ float cs[256], mv[256], hv[64];
    const int t = threadIdx.x;
    {
        float s0=0,s1=0,s2=0,s3=0,s4=0,s5=0,s6=0,s7=0;
#pragma unroll 2
        for (int sl = 0; sl < MSLOTS; sl += 8) {
            s0 += means[(sl+0)*256 + t]; s1 += means[(sl+1)*256 + t];
            s2 += means[(sl+2)*256 + t]; s3 += means[(sl+3)*256 + t];
            s4 += means[(sl+4)*256 + t]; s5 += means[(sl+5)*256 + t];
            s6 += means[(sl+6)*256 + t]; s7 += means[(sl+7)*256 + t];
        }
        cs[t] = ((s0+s1)+(s2+s3)) + ((s4+s5)+(s6+s7));
    }
    __syncthreads();
    {
        float s = 0.f;
        const unsigned short* wr = W16 + (long)t * C2;
#pragma unroll 4
        for (int k = 0; k < 256; k += 8) {
            uint4 w = *(const uint4*)(wr + k);
            s += cs[k]   * lo16f(w.x) + cs[k+1] * hi16f(w.x)
               + cs[k+2] * lo16f(w.y) + cs[k+3] * hi16f(w.y)
               + cs[k+4] * lo16f(w.z) + cs[k+5] * hi16f(w.z)
               + cs[k+6] * lo16f(w.w) + cs[k+7] * hi16f(w.w);
        }
        mv[t] = s * (1.0f / 25600.0f);
    }
    __syncthreads();
    if (t < 64) {
        const float* w1 = cvt + C_SEW1 + t * 256;
        float s = cvt[C_SEB1 + t];
        for (int cc = 0; cc < 256; cc += 4) {
            float4 w = *(const float4*)(w1 + cc);
            s += w.x * mv[cc] + w.y * mv[cc+1] + w.z * mv[cc+2] + w.w * mv[cc+3];
        }
        hv[t] = fmaxf(s, 0.f);
    }
    __syncthreads();
    {
        const float* w2 = cvt + C_SEW2 + t * 64;
        float s = cvt[C_SEB2 + t];
        for (int k = 0; k < 64; k += 4) {
            float4 w = *(const float4*)(w2 + k);
            s += w.x * hv[k] + w.y * hv[k+1] + w.z * hv[k+2] + w.w * hv[k+3];
        }
        sv_out[t] = 1.0f / (1.0f + __expf(-s));
    }
}

// ---------------------------------------------------------------------------
// Final: y-tile = xf@Wout^T (K=256) AND id-tile = xT@Wid^T (K=128, recomputed
// here instead of a stored idb round-trip), out[c][n] = y*sv + id,
// transposed store. Grid 1600, 256 thr. Staging via global_load_lds.
// ---------------------------------------------------------------------------
__global__ __launch_bounds__(256) void final_gemm_kernel(
    const unsigned short* __restrict__ x_probe,
    const unsigned short* __restrict__ A16,       // xf post-hop2 [NN][256]
    const unsigned short* __restrict__ W16,       // Wout bf16 [256][256]
    const unsigned short* __restrict__ AT16,      // xT bf16 [NN][128]
    const unsigned short* __restrict__ Wd16,      // Wid bf16 [256][128]
    const float* __restrict__ sv,
    void* __restrict__ outp)
{
    __shared__ SmemFu sm;
    const bool f32o = probe_f32(x_probe);
    const int tid = threadIdx.x;
    int m0, o0; gemm_tile_ids(blockIdx.x, m0, o0);
    const int lane = tid & 63, wv = tid >> 6;
    const int wm = wv >> 1, wn = wv & 1;
    const int lr = lane & 15, quad = lane >> 4;

    ffrag acc[2][2], accI[2][2];
#pragma unroll
    for (int mt = 0; mt < 2; ++mt)
#pragma unroll
        for (int nt = 0; nt < 2; ++nt) { acc[mt][nt] = (ffrag){0,0,0,0}; accI[mt][nt] = (ffrag){0,0,0,0}; }

    // y = xf @ Wout^T (K=256)
    for (int k0 = 0; k0 < 256; k0 += 64) {
        STAGE_TILE(sm.g.As, A16, m0, C2, k0)
        STAGE_TILE(sm.g.Bs, W16, o0, C2, k0)
        __syncthreads();
#pragma unroll
        for (int ks = 0; ks < 2; ++ks) {
            bfrag a[2], b[2];
#pragma unroll
            for (int mt = 0; mt < 2; ++mt)
                a[mt] = *fragp(sm.g.As, wm * 32 + mt * 16 + lr, ks * 4 + quad);
#pragma unroll
            for (int nt = 0; nt < 2; ++nt)
                b[nt] = *fragp(sm.g.Bs, wn * 32 + nt * 16 + lr, ks * 4 + quad);
#pragma unroll
            for (int mt = 0; mt < 2; ++mt)
#pragma unroll
                for (int nt = 0; nt < 2; ++nt)
                    acc[mt][nt] = __builtin_amdgcn_mfma_f32_16x16x32_bf16(a[mt], b[nt], acc[mt][nt], 0, 0, 0);
        }
        __syncthreads();
    }
    // id = xT @ Wid^T (K=128)
    for (int k0 = 0; k0 < 128; k0 += 64) {
        STAGE_TILE(sm.g.As, AT16, m0, 128, k0)
        STAGE_TILE(sm.g.Bs, Wd16, o0, 128, k0)
        __syncthreads();
#pragma unroll
        for (int ks = 0; ks < 2; ++ks) {
            bfrag a[2], b[2];
#pragma unroll
            for (int mt = 0; mt < 2; ++mt)
                a[mt] = *fragp(sm.g.As, wm * 32 + mt * 16 + lr, ks * 4 + quad);
#pragma unroll
            for (int nt = 0; nt < 2; ++nt)
                b[nt] = *fragp(sm.g.Bs, wn * 32 + nt * 16 + lr, ks * 4 + quad);
#pragma unroll
            for (int mt = 0; mt < 2; ++mt)
#pragma unroll
                for (int nt = 0; nt < 2; ++nt)
                    accI[mt][nt] = __builtin_amdgcn_mfma_f32_16x16x32_bf16(a[mt], b[nt], accI[mt][nt], 0, 0, 0);
        }
        __syncthreads();
    }

    // deposit y*sv + id into T[col][row] (fp32), then coalesced transposed store
#pragma unroll
    for (int mt = 0; mt < 2; ++mt)
#pragma unroll
        for (int nt = 0; nt < 2; ++nt) {
            int cl = wn * 32 + nt * 16 + lr;          // local col 0..63
            float s = sv[o0 + cl];
#pragma unroll
            for (int r = 0; r < 4; ++r) {
                int row = wm * 32 + mt * 16 + quad * 4 + r;
                float v = acc[mt][nt][r] * s + accI[mt][nt][r];
                sm.t.T[cl * 73 + row] = v;
            }
        }
    __syncthreads();
#pragma unroll
    for (int it = 0; it < 16; ++it) {
        int e = it * 256 + tid;
        int cc = e >> 6, nn = e & 63;
        long idx = (long)(o0 + cc) * NN + m0 + nn;
        float v = sm.t.T[cc * 73 + nn];
        if (f32o) ((float*)outp)[idx] = v;
        else      ((unsigned short*)outp)[idx] = f2b(v);
    }
}

extern "C" void kernel_launch(void* const* d_in, const int* in_sizes, int n_in,
                              void* d_out, int out_size, void* d_ws, size_t ws_size,
                              hipStream_t stream) {
    float* ws = (float*)d_ws;
    float* cvt   = ws;                          // C_END small fp32 params
    float* means = ws + 35200;                  // MSLOTS x 256
    float* svb   = means + MSLOTS * 256;        // 256
    float* als   = svb + 256;                   // 204800
    float* ald   = als + 204800;
    unsigned short* wb16  = (unsigned short*)(ald + 204800);  // 262144
    unsigned short* xT16  = wb16 + B_WEND;                    // 25600*128
    unsigned short* xf16  = xT16 + NN * 128;                  // 25600*256
    unsigned short* h16   = xf16 + NN * 256;                  // 25600*256

    const unsigned short* xp = (const unsigned short*)d_in[0];

    dim3 b256(256);

    prep_kernel<<<1600, b256, 0, stream>>>(
        xp, d_in[2], d_in[1], d_in[3], d_in[11],
        d_in[4], d_in[5], d_in[6], d_in[7], d_in[8], d_in[9], d_in[10],
        d_in[12], d_in[13], d_in[14], d_in[15],
        wb16, cvt, means, xT16);

    mfma_gemm_kernel<<<1600, b256, 0, stream>>>(
        xT16, wb16 + B_WIN, xf16);

    for (int l = 0; l < 2; ++l) {
        gat_gemm_kernel<<<1600, b256, 0, stream>>>(
            xf16, wb16 + B_WGAT + l * 65536, h16,
            cvt + C_ASRC + l * 256, cvt + C_ADST + l * 256, als, ald);
        aggregate_kernel<<<NN / 8, b256, 0, stream>>>(h16, als, ald,
            cvt + C_BNA + l * 256, cvt + C_BNB + l * 256, xf16,
            (l == 1) ? means : nullptr);
    }

    se_kernel<<<1, b256, 0, stream>>>(wb16 + B_WOUT, means, cvt, svb);

    final_gemm_kernel<<<1600, b256, 0, stream>>>(
        xp, xf16, wb16 + B_WOUT, xT16, wb16 + B_WID, svb, d_out);
}

// Round 17
// 193.323 us; speedup vs baseline: 1.1276x; 1.0212x over previous
//
#include <hip/hip_runtime.h>

#define NN 25600      // nodes = 160*160
#define HH 160
#define WW 160
#define C2 256
#define MSLOTS 64     // colsum atomic spreading slots

// ---- bf16 weight pack offsets (ushorts) ----
#define B_WIN   0
#define B_WID   32768
#define B_WGAT  65536      // 2 layers x 65536
#define B_WOUT  196608
#define B_WEND  262144

// ---- small fp32 param offsets inside cvt (floats) ----
#define C_BNA   0          // 2x256 BN scale
#define C_BNB   512        // 2x256 BN shift (bias/mean folded)
#define C_ASRC  1024       // 2x256
#define C_ADST  1536       // 2x256
#define C_SEW1  2048       // 64x256
#define C_SEB1  18432      // 64
#define C_SEW2  18496      // 256x64
#define C_SEB2  34880      // 256
#define C_END   35136

typedef __attribute__((ext_vector_type(8))) short bfrag;   // 8 bf16 (4 VGPRs)
typedef __attribute__((ext_vector_type(4))) float ffrag;   // 4 fp32 acc

__device__ __forceinline__ float b2f(unsigned short u) {
    union { unsigned int ui; float f; } v; v.ui = ((unsigned int)u) << 16; return v.f;
}
__device__ __forceinline__ unsigned short f2b(float f) {
    union { float f; unsigned int u; } v; v.f = f;
    unsigned int u = v.u;
    unsigned int r = (u + 0x7FFFu + ((u >> 16) & 1u)) >> 16;
    return (unsigned short)r;
}
__device__ __forceinline__ float lo16f(unsigned int w) {
    union { unsigned int ui; float f; } v; v.ui = w << 16; return v.f;
}
__device__ __forceinline__ float hi16f(unsigned int w) {
    union { unsigned int ui; float f; } v; v.ui = w & 0xFFFF0000u; return v.f;
}
// Wave-uniform dtype probe on first 512 halfwords of x.
__device__ __forceinline__ bool probe_f32(const unsigned short* __restrict__ x) {
    int l = threadIdx.x & 63;
    bool wild = false;
#pragma unroll
    for (int i = 0; i < 8; ++i) {
        float v = b2f(x[l * 8 + i]);
        wild |= !(fabsf(v) < 1e6f);
    }
    return __any(wild);
}
__device__ __forceinline__ float ldf(const void* p, long i, bool f32) {
    return f32 ? ((const float*)p)[i] : b2f(((const unsigned short*)p)[i]);
}

// XCD-grouping swizzle for the 1600-block GEMM grids (1600 = 8 XCDs x 200).
__device__ __forceinline__ void gemm_tile_ids(int bid, int& m0, int& o0) {
    int w = (bid & 7) * 200 + (bid >> 3);
    m0 = (w >> 2) * 64;
    o0 = (w & 3) * 64;
}

// Swizzled fragment pointer into an unpadded [64][64]-ushort LDS tile:
// chunk (16B) index is XOR'd with (row&7); matches the pre-swizzled
// global source used by the global_load_lds staging (rule: both sides).
__device__ __forceinline__ const bfrag* fragp(const unsigned short* buf, int row, int c8) {
    return (const bfrag*)(buf + row * 64 + ((c8 ^ (row & 7)) << 3));
}

// ---------------------------------------------------------------------------
// prep: pack weights bf16, fold BN, convert small params, zero means slots,
// AND transpose x -> bf16 [25600][128]. Grid = 1600 (16 nodes/block).
// ---------------------------------------------------------------------------
__global__ __launch_bounds__(256) void prep_kernel(
    const unsigned short* __restrict__ xp,
    const void* pwin, const void* pwid, const void* pwgat, const void* pwout,
    const void* pasrc, const void* padst, const void* pgbias,
    const void* pbng, const void* pbnb, const void* pbnm, const void* pbnv,
    const void* psew1, const void* pseb1, const void* psew2, const void* pseb2,
    unsigned short* __restrict__ wb, float* __restrict__ cvt,
    float* __restrict__ means, unsigned short* __restrict__ xT)
{
    __shared__ unsigned short T[16 * 136];
    const bool f32 = probe_f32(xp);
    const int tid = threadIdx.x;
    const int bid = blockIdx.x;
    const int gid = bid * 256 + tid;
    const int stride = gridDim.x * 256;

    for (int i = gid; i < MSLOTS * 256; i += stride) means[i] = 0.f;

    for (int i = gid; i < B_WEND; i += stride) {
        const void* s; int o;
        if      (i < B_WID)   { s = pwin;  o = i - B_WIN; }
        else if (i < B_WGAT)  { s = pwid;  o = i - B_WID; }
        else if (i < B_WOUT)  { s = pwgat; o = i - B_WGAT; }
        else                  { s = pwout; o = i - B_WOUT; }
        wb[i] = f32 ? f2b(((const float*)s)[o]) : ((const unsigned short*)s)[o];
    }
    for (int i = gid; i < 512; i += stride) {
        float sc = ldf(pbng, i, f32) * rsqrtf(ldf(pbnv, i, f32) + 1e-5f);
        cvt[C_BNA + i] = sc;
        cvt[C_BNB + i] = (ldf(pgbias, i, f32) - ldf(pbnm, i, f32)) * sc + ldf(pbnb, i, f32);
        cvt[C_ASRC + i] = ldf(pasrc, i, f32);
        cvt[C_ADST + i] = ldf(padst, i, f32);
    }
    for (int i = gid; i < 16384; i += stride) {
        cvt[C_SEW1 + i] = ldf(psew1, i, f32);
        cvt[C_SEW2 + i] = ldf(psew2, i, f32);
    }
    for (int i = gid; i < 64; i += stride)  cvt[C_SEB1 + i] = ldf(pseb1, i, f32);
    for (int i = gid; i < 256; i += stride) cvt[C_SEB2 + i] = ldf(pseb2, i, f32);

    // transpose slice: 16 nodes per block (grid 1600 covers 25600)
    {
        const int n0 = bid * 16;
        const int nl = tid & 15;           // node within block
        const int cb = tid >> 4;           // channel base lane group (0..15)
#pragma unroll
        for (int i = 0; i < 8; ++i) {
            int c = i * 16 + cb;
            long idx = (long)c * NN + n0 + nl;
            T[nl * 136 + c] = f32 ? f2b(((const float*)xp)[idx]) : xp[idx];
        }
        __syncthreads();
        {
            int n = tid >> 4, c0 = (tid & 15) * 8;   // 256 uint4 = 16 nodes x 128 c
            uint4 v = *(const uint4*)&T[n * 136 + c0];
            *(uint4*)(xT + (long)(n0 + n) * 128 + c0) = v;
        }
    }
}

// ---------------------------------------------------------------------------
// LDS layouts. Staging tiles UNPADDED [64][64] ushort, DOUBLE-BUFFERED
// (2-phase DMA pipeline: issue next tile's global_load_lds before computing
// the current one; one vmcnt-draining barrier per K-step).
// ---------------------------------------------------------------------------
struct SmemC64 { unsigned short Cs[64 * 72]; };                      //  9216 B
struct SmemGd  { unsigned short As[2][4096], Bs[2][4096]; };         // 32768 B
union  SmemNd  { SmemGd g; SmemC64 c; };
struct SmemT   { float T[64 * 73]; };                                // 18688 B
union  SmemFd  { SmemGd g; SmemT t; };

// Stage one 64x64-ushort tile via global_load_lds (pre-swizzled source chunk,
// lane-linear LDS dest). DST may be a runtime-selected (block-uniform) buffer.
#define STAGE_TILE(DST, SRC, ROW0, LDA, K0)                                       \
    {                                                                             \
        _Pragma("unroll")                                                         \
        for (int ii = 0; ii < 2; ++ii) {                                          \
            int e = tid + ii * 256;                                               \
            int row = e >> 3;                                                     \
            int q = (e & 7) ^ (row & 7);                                          \
            __builtin_amdgcn_global_load_lds(                                     \
                (const unsigned int*)((SRC) + (long)((ROW0) + row) * (LDA) + (K0) + q * 8), \
                (unsigned int*)&(DST)[e * 8], 16, 0, 0);                          \
        }                                                                         \
    }

// ---------------------------------------------------------------------------
// MFMA GEMM (K=128): xf16 = xT@Win^T. Grid 1600, 256 thr. 2-phase pipeline.
// ---------------------------------------------------------------------------
__global__ __launch_bounds__(256) void mfma_gemm_kernel(
    const unsigned short* __restrict__ A16,
    const unsigned short* __restrict__ Wi16,
    unsigned short* __restrict__ xf16)
{
    __shared__ SmemNd sm;
    const int tid = threadIdx.x;
    int m0, o0; gemm_tile_ids(blockIdx.x, m0, o0);
    const int lane = tid & 63, wv = tid >> 6;
    const int wm = wv >> 1, wn = wv & 1;
    const int lr = lane & 15, quad = lane >> 4;

    ffrag ai[2][2];
#pragma unroll
    for (int mt = 0; mt < 2; ++mt)
#pragma unroll
        for (int nt = 0; nt < 2; ++nt) ai[mt][nt] = (ffrag){0,0,0,0};

    STAGE_TILE(sm.g.As[0], A16,  m0, 128, 0)
    STAGE_TILE(sm.g.Bs[0], Wi16, o0, 128, 0)
    __syncthreads();
    int cur = 0;
#pragma unroll
    for (int s = 0; s < 2; ++s) {
        if (s == 0) {
            STAGE_TILE(sm.g.As[1], A16,  m0, 128, 64)
            STAGE_TILE(sm.g.Bs[1], Wi16, o0, 128, 64)
        }
#pragma unroll
        for (int ks = 0; ks < 2; ++ks) {
            bfrag a[2], bi[2];
#pragma unroll
            for (int mt = 0; mt < 2; ++mt)
                a[mt] = *fragp(sm.g.As[cur], wm * 32 + mt * 16 + lr, ks * 4 + quad);
#pragma unroll
            for (int nt = 0; nt < 2; ++nt)
                bi[nt] = *fragp(sm.g.Bs[cur], wn * 32 + nt * 16 + lr, ks * 4 + quad);
#pragma unroll
            for (int mt = 0; mt < 2; ++mt)
#pragma unroll
                for (int nt = 0; nt < 2; ++nt)
                    ai[mt][nt] = __builtin_amdgcn_mfma_f32_16x16x32_bf16(a[mt], bi[nt], ai[mt][nt], 0, 0, 0);
        }
        __syncthreads();
        cur ^= 1;
    }
    // epilogue: xf16
#pragma unroll
    for (int mt = 0; mt < 2; ++mt)
#pragma unroll
        for (int nt = 0; nt < 2; ++nt)
#pragma unroll
            for (int r = 0; r < 4; ++r)
                sm.c.Cs[(wm * 32 + mt * 16 + quad * 4 + r) * 72 + wn * 32 + nt * 16 + lr] = f2b(ai[mt][nt][r]);
    __syncthreads();
#pragma unroll
    for (int it = 0; it < 2; ++it) {
        int e = it * 256 + tid;
        int row = e >> 3, c8 = (e & 7) * 8;
        *(uint4*)(xf16 + (long)(m0 + row) * C2 + o0 + c8) = *(const uint4*)&sm.c.Cs[row * 72 + c8];
    }
}

// ---------------------------------------------------------------------------
// GAT GEMM (K=256): h = xf@W^T + fused attention scores. Grid 1600, 256 thr.
// 2-phase pipeline, 4 K-steps, one barrier per step.
// ---------------------------------------------------------------------------
__global__ __launch_bounds__(256) void gat_gemm_kernel(
    const unsigned short* __restrict__ A16,
    const unsigned short* __restrict__ W16,
    unsigned short* __restrict__ Cout,
    const float* __restrict__ asrc, const float* __restrict__ adst,
    float* __restrict__ als_out, float* __restrict__ ald_out)
{
    __shared__ SmemNd sm;
    const int tid = threadIdx.x;
    int m0, o0; gemm_tile_ids(blockIdx.x, m0, o0);
    const int lane = tid & 63, wv = tid >> 6;
    const int wm = wv >> 1, wn = wv & 1;
    const int lr = lane & 15, quad = lane >> 4;

    ffrag acc[2][2];
#pragma unroll
    for (int mt = 0; mt < 2; ++mt)
#pragma unroll
        for (int nt = 0; nt < 2; ++nt) acc[mt][nt] = (ffrag){0,0,0,0};

    STAGE_TILE(sm.g.As[0], A16, m0, C2, 0)
    STAGE_TILE(sm.g.Bs[0], W16, o0, C2, 0)
    __syncthreads();
    int cur = 0;
#pragma unroll
    for (int s = 0; s < 4; ++s) {
        if (s < 3) {
            STAGE_TILE(sm.g.As[cur ^ 1], A16, m0, C2, (s + 1) * 64)
            STAGE_TILE(sm.g.Bs[cur ^ 1], W16, o0, C2, (s + 1) * 64)
        }
#pragma unroll
        for (int ks = 0; ks < 2; ++ks) {
            bfrag a[2], b[2];
#pragma unroll
            for (int mt = 0; mt < 2; ++mt)
                a[mt] = *fragp(sm.g.As[cur], wm * 32 + mt * 16 + lr, ks * 4 + quad);
#pragma unroll
            for (int nt = 0; nt < 2; ++nt)
                b[nt] = *fragp(sm.g.Bs[cur], wn * 32 + nt * 16 + lr, ks * 4 + quad);
#pragma unroll
            for (int mt = 0; mt < 2; ++mt)
#pragma unroll
                for (int nt = 0; nt < 2; ++nt)
                    acc[mt][nt] = __builtin_amdgcn_mfma_f32_16x16x32_bf16(a[mt], b[nt], acc[mt][nt], 0, 0, 0);
        }
        __syncthreads();
        cur ^= 1;
    }
    // attention epilogue: wave covers head = (o0/32)+wn, d = nt*16+lr
    {
        const int head = (o0 >> 5) + wn;
        const float as0 = asrc[head * 32 + lr], as1 = asrc[head * 32 + 16 + lr];
        const float ad0 = adst[head * 32 + lr], ad1 = adst[head * 32 + 16 + lr];
#pragma unroll
        for (int mt = 0; mt < 2; ++mt)
#pragma unroll
            for (int r = 0; r < 4; ++r) {
                float ps = acc[mt][0][r] * as0 + acc[mt][1][r] * as1;
                float pd = acc[mt][0][r] * ad0 + acc[mt][1][r] * ad1;
#pragma unroll
                for (int sh = 1; sh < 16; sh <<= 1) {
                    ps += __shfl_xor(ps, sh);
                    pd += __shfl_xor(pd, sh);
                }
                if (lr == 0) {
                    int m = m0 + wm * 32 + mt * 16 + quad * 4 + r;
                    als_out[m * 8 + head] = ps;
                    ald_out[m * 8 + head] = pd;
                }
            }
    }
    // C store via LDS
#pragma unroll
    for (int mt = 0; mt < 2; ++mt)
#pragma unroll
        for (int nt = 0; nt < 2; ++nt)
#pragma unroll
            for (int r = 0; r < 4; ++r)
                sm.c.Cs[(wm * 32 + mt * 16 + quad * 4 + r) * 72 + wn * 32 + nt * 16 + lr] = f2b(acc[mt][nt][r]);
    __syncthreads();
#pragma unroll
    for (int it = 0; it < 2; ++it) {
        int e = it * 256 + tid;
        int row = e >> 3, c8 = (e & 7) * 8;
        *(uint4*)(Cout + (long)(m0 + row) * C2 + o0 + c8) = *(const uint4*)&sm.c.Cs[row * 72 + c8];
    }
}

// ---------------------------------------------------------------------------
// Aggregation: 8 nodes/block, 32 thr/node, 8 bf16 channels/thread. Grid 3200.
// BARRIER-FREE main path (per-thread register softmax, wave-broadcast loads).
// If means != nullptr (last hop): block-reduce colsum -> atomic slot spread.
// ---------------------------------------------------------------------------
__global__ __launch_bounds__(256) void aggregate_kernel(
    const unsigned short* __restrict__ h16,
    const float* __restrict__ al_s,
    const float* __restrict__ al_d,
    const float* __restrict__ bnA,
    const float* __restrict__ bnB,
    unsigned short* __restrict__ xf16,
    float* __restrict__ means)
{
    const int SI[11] = { 1, 1, 1, 0, 0, -1, -1, -1, -2,  0, 0};
    const int SJ[11] = { 1, 0,-1, 1,-1,  1,  0, -1,  0, -2, 0};
    __shared__ float part[4][256];

    const int t = threadIdx.x;
    const int ln = t >> 5;
    const int l = t & 31;
    const int n = blockIdx.x * 8 + ln;
    const int i = n / WW, j = n % WW;
    const int c8 = l * 8;
    const int hd = l >> 2;

    // neighbor indices + validity
    int srcn[11]; bool okm[11];
#pragma unroll
    for (int k = 0; k < 11; ++k) {
        int si = i + SI[k], sj = j + SJ[k];
        bool ok = (si >= 0) & (si < HH) & (sj >= 0) & (sj < WW);
        okm[k] = ok;
        srcn[k] = ok ? si * WW + sj : n;
    }

    // per-thread softmax over incoming edges for head hd
    float e[11];
    {
        const float ald = al_d[n * 8 + hd];
        float mx = -1e30f;
#pragma unroll
        for (int k = 0; k < 11; ++k) {
            float s = al_s[(long)srcn[k] * 8 + hd];
            float v = s + ald;
            v = v > 0.f ? v : 0.2f * v;
            v = okm[k] ? v : -1e30f;
            e[k] = v;
            mx = fmaxf(mx, v);
        }
        float denom = 0.f;
#pragma unroll
        for (int k = 0; k < 11; ++k) {
            float p = __expf(e[k] - mx);
            e[k] = p;
            denom += p;
        }
        const float inv = 1.f / (denom + 1e-16f);
#pragma unroll
        for (int k = 0; k < 11; ++k) e[k] *= inv;   // alpha
    }

    // batched gather: all 12 uint4 loads issued before any consumption
    uint4 hv[11];
#pragma unroll
    for (int k = 0; k < 11; ++k)
        hv[k] = *(const uint4*)(h16 + (long)srcn[k] * C2 + c8);
    uint4 rv = *(const uint4*)(xf16 + (long)n * C2 + c8);

    float a0=0.f,a1=0.f,a2=0.f,a3=0.f,a4=0.f,a5=0.f,a6=0.f,a7=0.f;
#pragma unroll
    for (int k = 0; k < 11; ++k) {
        float al = e[k];
        a0 += al * lo16f(hv[k].x); a1 += al * hi16f(hv[k].x);
        a2 += al * lo16f(hv[k].y); a3 += al * hi16f(hv[k].y);
        a4 += al * lo16f(hv[k].z); a5 += al * hi16f(hv[k].z);
        a6 += al * lo16f(hv[k].w); a7 += al * hi16f(hv[k].w);
    }
    float acc8[8] = {a0,a1,a2,a3,a4,a5,a6,a7};
    float res[8] = {lo16f(rv.x),hi16f(rv.x),lo16f(rv.y),hi16f(rv.y),
                    lo16f(rv.z),hi16f(rv.z),lo16f(rv.w),hi16f(rv.w)};
    float out[8];
#pragma unroll
    for (int q = 0; q < 8; ++q) {
        int c = c8 + q;
        float g = acc8[q] * bnA[c] + bnB[c];
        out[q] = fmaxf(g, 0.f) + res[q];
    }
    ushort4 o16a, o16b;
    o16a.x = f2b(out[0]); o16a.y = f2b(out[1]); o16a.z = f2b(out[2]); o16a.w = f2b(out[3]);
    o16b.x = f2b(out[4]); o16b.y = f2b(out[5]); o16b.z = f2b(out[6]); o16b.w = f2b(out[7]);
    *(ushort4*)(xf16 + (long)n * C2 + c8)     = o16a;
    *(ushort4*)(xf16 + (long)n * C2 + c8 + 4) = o16b;

    // fused colsum for SE (last hop only), atomic-spread over MSLOTS slots
    if (means) {
        float s8[8];
#pragma unroll
        for (int q = 0; q < 8; ++q) {
            s8[q] = out[q];
            s8[q] += __shfl_xor(s8[q], 32);    // combine node pair within wave
        }
        const int wvi = t >> 6;
        if ((t & 63) < 32) {
#pragma unroll
            for (int q = 0; q < 8; ++q) part[wvi][c8 + q] = s8[q];
        }
        __syncthreads();
        {
            float v = part[0][t] + part[1][t] + part[2][t] + part[3][t];
            atomicAdd(&means[(blockIdx.x & (MSLOTS - 1)) * 256 + t], v);
        }
    }
}

// ---------------------------------------------------------------------------
// SE vector, computed ONCE: cs = slot-sum(means); mv = cs@Wout^T / N;
// hv = relu(W1@mv + b1); sv = sigmoid(W2@hv + b2). Grid 1 x 256 thr.
// ---------------------------------------------------------------------------
__global__ __launch_bounds__(256) void se_kernel(
    const unsigned short* __restrict__ W16,     // Wout bf16 [256][256]
    const float* __restrict__ means,
    const float* __restrict__ cvt,
    float* __restrict__ sv_out)
{
    __shared__ float cs[256], mv[256], hv[64];
    const int t = threadIdx.x;
    {
        float s0=0,s1=0,s2=0,s3=0,s4=0,s5=0,s6=0,s7=0;
#pragma unroll 2
        for (int sl = 0; sl < MSLOTS; sl += 8) {
            s0 += means[(sl+0)*256 + t]; s1 += means[(sl+1)*256 + t];
            s2 += means[(sl+2)*256 + t]; s3 += means[(sl+3)*256 + t];
            s4 += means[(sl+4)*256 + t]; s5 += means[(sl+5)*256 + t];
            s6 += means[(sl+6)*256 + t]; s7 += means[(sl+7)*256 + t];
        }
        cs[t] = ((s0+s1)+(s2+s3)) + ((s4+s5)+(s6+s7));
    }
    __syncthreads();
    {
        float s = 0.f;
        const unsigned short* wr = W16 + (long)t * C2;
#pragma unroll 4
        for (int k = 0; k < 256; k += 8) {
            uint4 w = *(const uint4*)(wr + k);
            s += cs[k]   * lo16f(w.x) + cs[k+1] * hi16f(w.x)
               + cs[k+2] * lo16f(w.y) + cs[k+3] * hi16f(w.y)
               + cs[k+4] * lo16f(w.z) + cs[k+5] * hi16f(w.z)
               + cs[k+6] * lo16f(w.w) + cs[k+7] * hi16f(w.w);
        }
        mv[t] = s * (1.0f / 25600.0f);
    }
    __syncthreads();
    if (t < 64) {
        const float* w1 = cvt + C_SEW1 + t * 256;
        float s = cvt[C_SEB1 + t];
        for (int cc = 0; cc < 256; cc += 4) {
            float4 w = *(const float4*)(w1 + cc);
            s += w.x * mv[cc] + w.y * mv[cc+1] + w.z * mv[cc+2] + w.w * mv[cc+3];
        }
        hv[t] = fmaxf(s, 0.f);
    }
    __syncthreads();
    {
        const float* w2 = cvt + C_SEW2 + t * 64;
        float s = cvt[C_SEB2 + t];
        for (int k = 0; k < 64; k += 4) {
            float4 w = *(const float4*)(w2 + k);
            s += w.x * hv[k] + w.y * hv[k+1] + w.z * hv[k+2] + w.w * hv[k+3];
        }
        sv_out[t] = 1.0f / (1.0f + __expf(-s));
    }
}

// ---------------------------------------------------------------------------
// Final: y = xf@Wout^T (K=256) and id = xT@Wid^T (K=128) in one 6-step
// pipelined schedule; out[c][n] = y*sv + id, transposed store. Grid 1600.
// ---------------------------------------------------------------------------
__global__ __launch_bounds__(256) void final_gemm_kernel(
    const unsigned short* __restrict__ x_probe,
    const unsigned short* __restrict__ A16,       // xf post-hop2 [NN][256]
    const unsigned short* __restrict__ W16,       // Wout bf16 [256][256]
    const unsigned short* __restrict__ AT16,      // xT bf16 [NN][128]
    const unsigned short* __restrict__ Wd16,      // Wid bf16 [256][128]
    const float* __restrict__ sv,
    void* __restrict__ outp)
{
    __shared__ SmemFd sm;
    const bool f32o = probe_f32(x_probe);
    const int tid = threadIdx.x;
    int m0, o0; gemm_tile_ids(blockIdx.x, m0, o0);
    const int lane = tid & 63, wv = tid >> 6;
    const int wm = wv >> 1, wn = wv & 1;
    const int lr = lane & 15, quad = lane >> 4;

    ffrag acc[2][2], accI[2][2];
#pragma unroll
    for (int mt = 0; mt < 2; ++mt)
#pragma unroll
        for (int nt = 0; nt < 2; ++nt) { acc[mt][nt] = (ffrag){0,0,0,0}; accI[mt][nt] = (ffrag){0,0,0,0}; }

    // 6-step unified schedule: steps 0..3 = y (K=256), steps 4..5 = id (K=128)
    STAGE_TILE(sm.g.As[0], A16, m0, C2, 0)
    STAGE_TILE(sm.g.Bs[0], W16, o0, C2, 0)
    __syncthreads();
    int cur = 0;
#pragma unroll
    for (int s = 0; s < 6; ++s) {
        if (s < 3) {
            STAGE_TILE(sm.g.As[cur ^ 1], A16, m0, C2, (s + 1) * 64)
            STAGE_TILE(sm.g.Bs[cur ^ 1], W16, o0, C2, (s + 1) * 64)
        } else if (s == 3) {
            STAGE_TILE(sm.g.As[cur ^ 1], AT16, m0, 128, 0)
            STAGE_TILE(sm.g.Bs[cur ^ 1], Wd16, o0, 128, 0)
        } else if (s == 4) {
            STAGE_TILE(sm.g.As[cur ^ 1], AT16, m0, 128, 64)
            STAGE_TILE(sm.g.Bs[cur ^ 1], Wd16, o0, 128, 64)
        }
        if (s < 4) {
#pragma unroll
            for (int ks = 0; ks < 2; ++ks) {
                bfrag a[2], b[2];
#pragma unroll
                for (int mt = 0; mt < 2; ++mt)
                    a[mt] = *fragp(sm.g.As[cur], wm * 32 + mt * 16 + lr, ks * 4 + quad);
#pragma unroll
                for (int nt = 0; nt < 2; ++nt)
                    b[nt] = *fragp(sm.g.Bs[cur], wn * 32 + nt * 16 + lr, ks * 4 + quad);
#pragma unroll
                for (int mt = 0; mt < 2; ++mt)
#pragma unroll
                    for (int nt = 0; nt < 2; ++nt)
                        acc[mt][nt] = __builtin_amdgcn_mfma_f32_16x16x32_bf16(a[mt], b[nt], acc[mt][nt], 0, 0, 0);
            }
        } else {
#pragma unroll
            for (int ks = 0; ks < 2; ++ks) {
                bfrag a[2], b[2];
#pragma unroll
                for (int mt = 0; mt < 2; ++mt)
                    a[mt] = *fragp(sm.g.As[cur], wm * 32 + mt * 16 + lr, ks * 4 + quad);
#pragma unroll
                for (int nt = 0; nt < 2; ++nt)
                    b[nt] = *fragp(sm.g.Bs[cur], wn * 32 + nt * 16 + lr, ks * 4 + quad);
#pragma unroll
                for (int mt = 0; mt < 2; ++mt)
#pragma unroll
                    for (int nt = 0; nt < 2; ++nt)
                        accI[mt][nt] = __builtin_amdgcn_mfma_f32_16x16x32_bf16(a[mt], b[nt], accI[mt][nt], 0, 0, 0);
            }
        }
        __syncthreads();
        cur ^= 1;
    }

    // deposit y*sv + id into T[col][row] (fp32), then coalesced transposed store
#pragma unroll
    for (int mt = 0; mt < 2; ++mt)
#pragma unroll
        for (int nt = 0; nt < 2; ++nt) {
            int cl = wn * 32 + nt * 16 + lr;          // local col 0..63
            float s = sv[o0 + cl];
#pragma unroll
            for (int r = 0; r < 4; ++r) {
                int row = wm * 32 + mt * 16 + quad * 4 + r;
                float v = acc[mt][nt][r] * s + accI[mt][nt][r];
                sm.t.T[cl * 73 + row] = v;
            }
        }
    __syncthreads();
#pragma unroll
    for (int it = 0; it < 16; ++it) {
        int e = it * 256 + tid;
        int cc = e >> 6, nn = e & 63;
        long idx = (long)(o0 + cc) * NN + m0 + nn;
        float v = sm.t.T[cc * 73 + nn];
        if (f32o) ((float*)outp)[idx] = v;
        else      ((unsigned short*)outp)[idx] = f2b(v);
    }
}

extern "C" void kernel_launch(void* const* d_in, const int* in_sizes, int n_in,
                              void* d_out, int out_size, void* d_ws, size_t ws_size,
                              hipStream_t stream) {
    float* ws = (float*)d_ws;
    float* cvt   = ws;                          // C_END small fp32 params
    float* means = ws + 35200;                  // MSLOTS x 256
    float* svb   = means + MSLOTS * 256;        // 256
    float* als   = svb + 256;                   // 204800
    float* ald   = als + 204800;
    unsigned short* wb16  = (unsigned short*)(ald + 204800);  // 262144
    unsigned short* xT16  = wb16 + B_WEND;                    // 25600*128
    unsigned short* xf16  = xT16 + NN * 128;                  // 25600*256
    unsigned short* h16   = xf16 + NN * 256;                  // 25600*256

    const unsigned short* xp = (const unsigned short*)d_in[0];

    dim3 b256(256);

    prep_kernel<<<1600, b256, 0, stream>>>(
        xp, d_in[2], d_in[1], d_in[3], d_in[11],
        d_in[4], d_in[5], d_in[6], d_in[7], d_in[8], d_in[9], d_in[10],
        d_in[12], d_in[13], d_in[14], d_in[15],
        wb16, cvt, means, xT16);

    mfma_gemm_kernel<<<1600, b256, 0, stream>>>(
        xT16, wb16 + B_WIN, xf16);

    for (int l = 0; l < 2; ++l) {
        gat_gemm_kernel<<<1600, b256, 0, stream>>>(
            xf16, wb16 + B_WGAT + l * 65536, h16,
            cvt + C_ASRC + l * 256, cvt + C_ADST + l * 256, als, ald);
        aggregate_kernel<<<NN / 8, b256, 0, stream>>>(h16, als, ald,
            cvt + C_BNA + l * 256, cvt + C_BNB + l * 256, xf16,
            (l == 1) ? means : nullptr);
    }

    se_kernel<<<1, b256, 0, stream>>>(wb16 + B_WOUT, means, cvt, svb);

    final_gemm_kernel<<<1600, b256, 0, stream>>>(
        xp, xf16, wb16 + B_WOUT, xT16, wb16 + B_WID, svb, d_out);
}